// Round 1
// baseline (16088.907 us; speedup 1.0000x reference)
//
#include <hip/hip_runtime.h>
#include <math.h>

#define NPTS 1024
#define DIM  128
#define BATCH 16
#define NCLOUD 32
#define BIGF 3.0e38f

// ws layout:
//   offset 0   : double mse_sum (zeroed via hipMemsetAsync each launch)
//   offset 64  : float sorted_deaths[32][1024]  (128 KB)

// ---------------- MSE partial-sum kernel ----------------
__global__ __launch_bounds__(256) void mse_kernel(const float* __restrict__ a,
                                                  const float* __restrict__ b,
                                                  double* __restrict__ acc, int n4) {
  int i = blockIdx.x * blockDim.x + threadIdx.x;
  int stride = gridDim.x * blockDim.x;
  const float4* a4 = (const float4*)a;
  const float4* b4 = (const float4*)b;
  float s = 0.f;
  for (int k = i; k < n4; k += stride) {
    float4 va = a4[k], vb = b4[k];
    float dx = va.x - vb.x, dy = va.y - vb.y, dz = va.z - vb.z, dw = va.w - vb.w;
    s += dx * dx + dy * dy + dz * dz + dw * dw;
  }
  #pragma unroll
  for (int off = 32; off; off >>= 1) s += __shfl_xor(s, off);
  __shared__ float wsum[4];
  int lane = threadIdx.x & 63, wid = threadIdx.x >> 6;
  if (lane == 0) wsum[wid] = s;
  __syncthreads();
  if (threadIdx.x == 0)
    atomicAdd(acc, (double)(wsum[0] + wsum[1] + wsum[2] + wsum[3]));
}

// ---------------- Prim MST + bitonic sort, one block per cloud ----------------
// cloud c: b = c & 15, src = c >> 4 (0 -> x1, 1 -> x2)
__global__ __launch_bounds__(1024) void prim_kernel(const float* __restrict__ x1,
                                                    const float* __restrict__ x2,
                                                    float* __restrict__ sorted_out) {
  const int cloud = blockIdx.x;
  const int b = cloud & (BATCH - 1);
  const int src = cloud >> 4;
  const float* xbase = (src ? x2 : x1) + (size_t)b * NPTS * DIM;
  const int j = threadIdx.x;  // node owned by this thread

  __shared__ float xi_sh[DIM];     // staged x[cur]
  __shared__ float sq_sh[NPTS];    // |x_j|^2
  __shared__ float redw[16];
  __shared__ int   redi[16];
  __shared__ float deaths[NPTS];

  // precompute |x_j|^2
  const float4* xr = (const float4*)(xbase + (size_t)j * DIM);
  {
    float ax = 0.f, ay = 0.f, az = 0.f, aw = 0.f;
    #pragma unroll 8
    for (int m = 0; m < DIM / 4; ++m) {
      float4 v = xr[m];
      ax = fmaf(v.x, v.x, ax);
      ay = fmaf(v.y, v.y, ay);
      az = fmaf(v.z, v.z, az);
      aw = fmaf(v.w, v.w, aw);
    }
    sq_sh[j] = (ax + ay) + (az + aw);
  }
  const float sqj = sq_sh[j];  // own value, no race (same thread wrote it)

  float mind   = BIGF;
  bool in_tree = (j == 0);
  int  cur     = 0;

  for (int t = 0; t < NPTS - 1; ++t) {
    // stage x[cur] into LDS (one wave-quarter does float4 loads)
    if (threadIdx.x < DIM / 4) {
      ((float4*)xi_sh)[threadIdx.x] = ((const float4*)(xbase + (size_t)cur * DIM))[threadIdx.x];
    }
    __syncthreads();  // B1: xi_sh (and iter-0 sq_sh) visible

    // d(cur, j)
    const float4* xi4 = (const float4*)xi_sh;
    float ax = 0.f, ay = 0.f, az = 0.f, aw = 0.f;
    #pragma unroll 8
    for (int m = 0; m < DIM / 4; ++m) {
      float4 v = xr[m];   // own row, L2-hot
      float4 u = xi4[m];  // broadcast from LDS
      ax = fmaf(v.x, u.x, ax);
      ay = fmaf(v.y, u.y, ay);
      az = fmaf(v.z, u.z, az);
      aw = fmaf(v.w, u.w, aw);
    }
    float dot = (ax + ay) + (az + aw);
    float d2  = sq_sh[cur] + sqj - 2.f * dot;
    float d   = sqrtf(fmaxf(d2, 0.f) + 1e-12f);

    // masked min-update (reference: mind = where(in_tree, inf, min(mind, D[cur])))
    mind = in_tree ? BIGF : fminf(mind, d);

    // argmin reduce: wave-level shuffle pairs, then per-wave leaders to LDS
    float w  = mind;
    int   idx = j;
    #pragma unroll
    for (int off = 32; off; off >>= 1) {
      float w2 = __shfl_xor(w, off);
      int   i2 = __shfl_xor(idx, off);
      if (w2 < w || (w2 == w && i2 < idx)) { w = w2; idx = i2; }
    }
    int lane = j & 63, wid = j >> 6;
    if (lane == 0) { redw[wid] = w; redi[wid] = idx; }
    __syncthreads();  // B2: redw/redi visible

    // every thread scans the 16 wave results (broadcast LDS reads, no 3rd barrier)
    float cw = redw[0];
    int   ci = redi[0];
    #pragma unroll
    for (int q = 1; q < 16; ++q) {
      float w2 = redw[q];
      int   i2 = redi[q];
      if (w2 < cw || (w2 == cw && i2 < ci)) { cw = w2; ci = i2; }
    }
    if (j == ci) in_tree = true;
    if (j == 0)  deaths[t] = cw;
    cur = ci;
  }

  if (threadIdx.x == 0) deaths[NPTS - 1] = BIGF;  // pad for power-of-2 sort
  __syncthreads();

  // bitonic sort ascending, 1024 elements in LDS
  for (int k = 2; k <= NPTS; k <<= 1) {
    for (int jj = k >> 1; jj > 0; jj >>= 1) {
      int i = threadIdx.x;
      int l = i ^ jj;
      if (l > i) {
        float va = deaths[i], vb = deaths[l];
        bool up = ((i & k) == 0);
        if ((va > vb) == up) { deaths[i] = vb; deaths[l] = va; }
      }
      __syncthreads();
    }
  }

  sorted_out[(size_t)cloud * NPTS + threadIdx.x] = deaths[threadIdx.x];
}

// ---------------- final combine ----------------
__global__ __launch_bounds__(1024) void final_kernel(const double* __restrict__ mse_acc,
                                                     const float* __restrict__ sorted,
                                                     float* __restrict__ out) {
  int wid = threadIdx.x >> 6;   // batch id, 16 waves
  int lane = threadIdx.x & 63;
  const float* s1 = sorted + (size_t)wid * NPTS;
  const float* s2 = sorted + (size_t)(BATCH + wid) * NPTS;
  float s = 0.f;
  for (int k = lane; k < NPTS; k += 64) {  // index 1023: BIGF-BIGF = 0
    float dlt = s1[k] - s2[k];
    s += dlt * dlt;
  }
  #pragma unroll
  for (int off = 32; off; off >>= 1) s += __shfl_xor(s, off);
  __shared__ float part[16];
  if (lane == 0) part[wid] = sqrtf(s);
  __syncthreads();
  if (threadIdx.x == 0) {
    float topo = 0.f;
    #pragma unroll
    for (int q = 0; q < 16; ++q) topo += part[q];
    float mse = (float)(mse_acc[0] / (double)((size_t)BATCH * NPTS * DIM));
    out[0] = 1.0f * mse + 0.1f * topo;
  }
}

extern "C" void kernel_launch(void* const* d_in, const int* in_sizes, int n_in,
                              void* d_out, int out_size, void* d_ws, size_t ws_size,
                              hipStream_t stream) {
  const float* x1 = (const float*)d_in[0];
  const float* x2 = (const float*)d_in[1];
  double* mse_acc = (double*)d_ws;
  float* sorted   = (float*)((char*)d_ws + 64);
  float* out      = (float*)d_out;

  hipMemsetAsync(d_ws, 0, 64, stream);

  int n4 = (BATCH * NPTS * DIM) / 4;
  mse_kernel<<<1024, 256, 0, stream>>>(x1, x2, mse_acc, n4);
  prim_kernel<<<NCLOUD, NPTS, 0, stream>>>(x1, x2, sorted);
  final_kernel<<<1, NPTS, 0, stream>>>(mse_acc, sorted, out);
}

// Round 2
// 1706.583 us; speedup vs baseline: 9.4276x; 9.4276x over previous
//
#include <hip/hip_runtime.h>
#include <math.h>

#define NPTS 1024
#define DIM  128
#define BATCH 16
#define NCLOUD 32
#define BIGF 3.0e38f

// ws layout (fast path):
//   [0, 64)            : double mse_sum
//   [64, 64+128K)      : float deaths[32][1024] (later sorted in-place)
//   [196608, +128MB)   : float D[32][1024][1024]
#define DEATHS_OFF 64
#define D_OFF 196608
#define WS_NEED ((size_t)D_OFF + (size_t)NCLOUD * NPTS * NPTS * 4)

// ---------------- MSE partial-sum kernel ----------------
__global__ __launch_bounds__(256) void mse_kernel(const float* __restrict__ a,
                                                  const float* __restrict__ b,
                                                  double* __restrict__ acc, int n4) {
  int i = blockIdx.x * blockDim.x + threadIdx.x;
  int stride = gridDim.x * blockDim.x;
  const float4* a4 = (const float4*)a;
  const float4* b4 = (const float4*)b;
  float s = 0.f;
  for (int k = i; k < n4; k += stride) {
    float4 va = a4[k], vb = b4[k];
    float dx = va.x - vb.x, dy = va.y - vb.y, dz = va.z - vb.z, dw = va.w - vb.w;
    s += dx * dx + dy * dy + dz * dz + dw * dw;
  }
  #pragma unroll
  for (int off = 32; off; off >>= 1) s += __shfl_xor(s, off);
  __shared__ float wsum[4];
  int lane = threadIdx.x & 63, wid = threadIdx.x >> 6;
  if (lane == 0) wsum[wid] = s;
  __syncthreads();
  if (threadIdx.x == 0)
    atomicAdd(acc, (double)(wsum[0] + wsum[1] + wsum[2] + wsum[3]));
}

// ---------------- distance-matrix kernel (fast path) ----------------
// Tile: 32 i-rows x 64 j-cols per block, 256 threads, one cloud per blockIdx.z.
// tx (tid&15) -> 4 consecutive j's (coalesced stores); ty (tid>>4) -> 2 i's.
// Accumulation pattern bitwise-matches the reference-kernel dot:
// per-float4 component accumulators, dot = (ax+ay)+(az+aw).
__global__ __launch_bounds__(256) void distmat_kernel(const float* __restrict__ x1,
                                                      const float* __restrict__ x2,
                                                      float* __restrict__ Dmat) {
  const int cloud = blockIdx.z;
  const int b = cloud & (BATCH - 1);
  const int src = cloud >> 4;
  const float* xc = (src ? x2 : x1) + (size_t)b * NPTS * DIM;
  float* Dc = Dmat + ((size_t)cloud << 20);

  const int i0 = blockIdx.y * 32;
  const int j0 = blockIdx.x * 64;
  const int tid = threadIdx.x;

  __shared__ float xi_sh[32 * 132];        // padded rows (132 floats, 16B-aligned rows)
  __shared__ float xj_sh[64 * 32 * 4];     // f4-swizzled: pos = r*32 + (c ^ (((r>>2)&7)<<2))
  __shared__ float sqi_sh[32];
  __shared__ float sqj_sh[64];

  // stage i-tile
  for (int k = tid; k < 32 * 32; k += 256) {
    int r = k >> 5, c = k & 31;
    float4 v = ((const float4*)(xc + (size_t)(i0 + r) * DIM))[c];
    *((float4*)&xi_sh[r * 132 + c * 4]) = v;
  }
  // stage j-tile (swizzled)
  for (int k = tid; k < 64 * 32; k += 256) {
    int r = k >> 5, c = k & 31;
    float4 v = ((const float4*)(xc + (size_t)(j0 + r) * DIM))[c];
    int cs = c ^ (((r >> 2) & 7) << 2);
    ((float4*)xj_sh)[r * 32 + cs] = v;
  }
  __syncthreads();

  // squared norms (same accumulation pattern as reference kernel)
  if (tid < 32) {
    float ax = 0.f, ay = 0.f, az = 0.f, aw = 0.f;
    #pragma unroll 8
    for (int c = 0; c < 32; ++c) {
      float4 v = *((float4*)&xi_sh[tid * 132 + c * 4]);
      ax = fmaf(v.x, v.x, ax); ay = fmaf(v.y, v.y, ay);
      az = fmaf(v.z, v.z, az); aw = fmaf(v.w, v.w, aw);
    }
    sqi_sh[tid] = (ax + ay) + (az + aw);
  } else if (tid < 96) {
    int r = tid - 32;
    int sw = ((r >> 2) & 7) << 2;
    float ax = 0.f, ay = 0.f, az = 0.f, aw = 0.f;
    #pragma unroll 8
    for (int c = 0; c < 32; ++c) {
      float4 v = ((float4*)xj_sh)[r * 32 + (c ^ sw)];
      ax = fmaf(v.x, v.x, ax); ay = fmaf(v.y, v.y, ay);
      az = fmaf(v.z, v.z, az); aw = fmaf(v.w, v.w, aw);
    }
    sqj_sh[r] = (ax + ay) + (az + aw);
  }
  __syncthreads();

  const int tx = tid & 15, ty = tid >> 4;
  const int swj = (tx & 7) << 2;  // ((row>>2)&7)<<2 with row = tx*4+jj, jj<4
  float4 acc[2][4];
  #pragma unroll
  for (int ii = 0; ii < 2; ++ii)
    #pragma unroll
    for (int jj = 0; jj < 4; ++jj)
      acc[ii][jj] = make_float4(0.f, 0.f, 0.f, 0.f);

  const float4* xi4 = (const float4*)xi_sh;
  const float4* xj4 = (const float4*)xj_sh;

  #pragma unroll 4
  for (int m = 0; m < 32; ++m) {
    float4 va[2], vb[4];
    #pragma unroll
    for (int ii = 0; ii < 2; ++ii) va[ii] = xi4[(ty * 2 + ii) * 33 + m];
    #pragma unroll
    for (int jj = 0; jj < 4; ++jj) vb[jj] = xj4[(tx * 4 + jj) * 32 + (m ^ swj)];
    #pragma unroll
    for (int ii = 0; ii < 2; ++ii)
      #pragma unroll
      for (int jj = 0; jj < 4; ++jj) {
        acc[ii][jj].x = fmaf(va[ii].x, vb[jj].x, acc[ii][jj].x);
        acc[ii][jj].y = fmaf(va[ii].y, vb[jj].y, acc[ii][jj].y);
        acc[ii][jj].z = fmaf(va[ii].z, vb[jj].z, acc[ii][jj].z);
        acc[ii][jj].w = fmaf(va[ii].w, vb[jj].w, acc[ii][jj].w);
      }
  }

  #pragma unroll
  for (int ii = 0; ii < 2; ++ii) {
    int il = ty * 2 + ii;
    int gi = i0 + il;
    float o[4];
    #pragma unroll
    for (int jj = 0; jj < 4; ++jj) {
      int jl = tx * 4 + jj;
      int gj = j0 + jl;
      float dot = (acc[ii][jj].x + acc[ii][jj].y) + (acc[ii][jj].z + acc[ii][jj].w);
      float d2 = sqi_sh[il] + sqj_sh[jl] - 2.f * dot;
      float d = sqrtf(fmaxf(d2, 0.f) + 1e-12f);
      o[jj] = (gi == gj) ? BIGF : d;
    }
    *((float4*)&Dc[(size_t)gi * NPTS + j0 + tx * 4]) = make_float4(o[0], o[1], o[2], o[3]);
  }
}

// ---------------- single-wave Prim on precomputed D (fast path) ----------------
__global__ __launch_bounds__(64) void prim_fast(const float* __restrict__ Dmat,
                                                float* __restrict__ deaths_out) {
  const int cloud = blockIdx.x;
  const int lane = threadIdx.x;
  const float* Dc = Dmat + ((size_t)cloud << 20);

  float mind[16];
  int mask = 0;
  #pragma unroll
  for (int m = 0; m < 16; ++m) mind[m] = Dc[m * 64 + lane];  // row 0
  if (lane == 0) { mind[0] = BIGF; mask = 1; }               // node 0 in tree

  __shared__ float dsh[NPTS];

  for (int t = 0; t < NPTS - 1; ++t) {
    // thread-local argmin over 16 owned nodes (ascending m => first-index ties)
    float w = BIGF;
    int bj = 0x7fffffff;
    #pragma unroll
    for (int m = 0; m < 16; ++m) {
      float v = mind[m];
      int j = m * 64 + lane;
      bool lt = v < w;
      w = lt ? v : w;
      bj = lt ? j : bj;
    }
    // wave butterfly argmin, first-index tie-break
    #pragma unroll
    for (int off = 32; off; off >>= 1) {
      float w2 = __shfl_xor(w, off);
      int j2 = __shfl_xor(bj, off);
      if (w2 < w || (w2 == w && j2 < bj)) { w = w2; bj = j2; }
    }
    if (lane == 0) dsh[t] = w;

    // mark cur in-tree (static reg indices only)
    int cm = bj >> 6, cl = bj & 63;
    #pragma unroll
    for (int m = 0; m < 16; ++m)
      if (m == cm && lane == cl) { mind[m] = BIGF; mask |= (1 << m); }

    // load D[cur] row, masked min-update
    const float* row = Dc + ((size_t)bj << 10);
    float dv[16];
    #pragma unroll
    for (int m = 0; m < 16; ++m) dv[m] = row[m * 64 + lane];
    #pragma unroll
    for (int m = 0; m < 16; ++m)
      if (!((mask >> m) & 1)) mind[m] = fminf(mind[m], dv[m]);
  }

  if (lane == 0) dsh[NPTS - 1] = BIGF;  // pad for sort
  __syncthreads();
  #pragma unroll
  for (int m = 0; m < 16; ++m) {
    int k = m * 64 + lane;
    deaths_out[(size_t)cloud * NPTS + k] = dsh[k];
  }
}

// ---------------- bitonic sort kernel (fast path) ----------------
__global__ __launch_bounds__(1024) void sort_kernel(float* __restrict__ buf) {
  __shared__ float s[NPTS];
  int tid = threadIdx.x;
  float* base = buf + (size_t)blockIdx.x * NPTS;
  s[tid] = base[tid];
  __syncthreads();
  for (int k = 2; k <= NPTS; k <<= 1) {
    for (int jj = k >> 1; jj > 0; jj >>= 1) {
      int i = tid;
      int l = i ^ jj;
      if (l > i) {
        float va = s[i], vb = s[l];
        bool up = ((i & k) == 0);
        if ((va > vb) == up) { s[i] = vb; s[l] = va; }
      }
      __syncthreads();
    }
  }
  base[tid] = s[tid];
}

// ---------------- fallback: round-0 fused Prim+sort (1 block / cloud) ----------------
__global__ __launch_bounds__(1024) void prim_kernel(const float* __restrict__ x1,
                                                    const float* __restrict__ x2,
                                                    float* __restrict__ sorted_out) {
  const int cloud = blockIdx.x;
  const int b = cloud & (BATCH - 1);
  const int src = cloud >> 4;
  const float* xbase = (src ? x2 : x1) + (size_t)b * NPTS * DIM;
  const int j = threadIdx.x;

  __shared__ float xi_sh[DIM];
  __shared__ float sq_sh[NPTS];
  __shared__ float redw[16];
  __shared__ int   redi[16];
  __shared__ float deaths[NPTS];

  const float4* xr = (const float4*)(xbase + (size_t)j * DIM);
  {
    float ax = 0.f, ay = 0.f, az = 0.f, aw = 0.f;
    #pragma unroll 8
    for (int m = 0; m < DIM / 4; ++m) {
      float4 v = xr[m];
      ax = fmaf(v.x, v.x, ax); ay = fmaf(v.y, v.y, ay);
      az = fmaf(v.z, v.z, az); aw = fmaf(v.w, v.w, aw);
    }
    sq_sh[j] = (ax + ay) + (az + aw);
  }
  const float sqj = sq_sh[j];

  float mind = BIGF;
  bool in_tree = (j == 0);
  int  cur = 0;

  for (int t = 0; t < NPTS - 1; ++t) {
    if (threadIdx.x < DIM / 4)
      ((float4*)xi_sh)[threadIdx.x] = ((const float4*)(xbase + (size_t)cur * DIM))[threadIdx.x];
    __syncthreads();

    const float4* xi4 = (const float4*)xi_sh;
    float ax = 0.f, ay = 0.f, az = 0.f, aw = 0.f;
    #pragma unroll 8
    for (int m = 0; m < DIM / 4; ++m) {
      float4 v = xr[m];
      float4 u = xi4[m];
      ax = fmaf(v.x, u.x, ax); ay = fmaf(v.y, u.y, ay);
      az = fmaf(v.z, u.z, az); aw = fmaf(v.w, u.w, aw);
    }
    float dot = (ax + ay) + (az + aw);
    float d2 = sq_sh[cur] + sqj - 2.f * dot;
    float d = sqrtf(fmaxf(d2, 0.f) + 1e-12f);
    mind = in_tree ? BIGF : fminf(mind, d);

    float w = mind;
    int idx = j;
    #pragma unroll
    for (int off = 32; off; off >>= 1) {
      float w2 = __shfl_xor(w, off);
      int i2 = __shfl_xor(idx, off);
      if (w2 < w || (w2 == w && i2 < idx)) { w = w2; idx = i2; }
    }
    int lane = j & 63, wid = j >> 6;
    if (lane == 0) { redw[wid] = w; redi[wid] = idx; }
    __syncthreads();

    float cw = redw[0];
    int ci = redi[0];
    #pragma unroll
    for (int q = 1; q < 16; ++q) {
      float w2 = redw[q]; int i2 = redi[q];
      if (w2 < cw || (w2 == cw && i2 < ci)) { cw = w2; ci = i2; }
    }
    if (j == ci) in_tree = true;
    if (j == 0)  deaths[t] = cw;
    cur = ci;
  }

  if (threadIdx.x == 0) deaths[NPTS - 1] = BIGF;
  __syncthreads();

  for (int k = 2; k <= NPTS; k <<= 1) {
    for (int jj = k >> 1; jj > 0; jj >>= 1) {
      int i = threadIdx.x;
      int l = i ^ jj;
      if (l > i) {
        float va = deaths[i], vb = deaths[l];
        bool up = ((i & k) == 0);
        if ((va > vb) == up) { deaths[i] = vb; deaths[l] = va; }
      }
      __syncthreads();
    }
  }
  sorted_out[(size_t)cloud * NPTS + threadIdx.x] = deaths[threadIdx.x];
}

// ---------------- final combine ----------------
__global__ __launch_bounds__(1024) void final_kernel(const double* __restrict__ mse_acc,
                                                     const float* __restrict__ sorted,
                                                     float* __restrict__ out) {
  int wid = threadIdx.x >> 6;
  int lane = threadIdx.x & 63;
  const float* s1 = sorted + (size_t)wid * NPTS;
  const float* s2 = sorted + (size_t)(BATCH + wid) * NPTS;
  float s = 0.f;
  for (int k = lane; k < NPTS; k += 64) {
    float dlt = s1[k] - s2[k];
    s += dlt * dlt;
  }
  #pragma unroll
  for (int off = 32; off; off >>= 1) s += __shfl_xor(s, off);
  __shared__ float part[16];
  if (lane == 0) part[wid] = sqrtf(s);
  __syncthreads();
  if (threadIdx.x == 0) {
    float topo = 0.f;
    #pragma unroll
    for (int q = 0; q < 16; ++q) topo += part[q];
    float mse = (float)(mse_acc[0] / (double)((size_t)BATCH * NPTS * DIM));
    out[0] = 1.0f * mse + 0.1f * topo;
  }
}

extern "C" void kernel_launch(void* const* d_in, const int* in_sizes, int n_in,
                              void* d_out, int out_size, void* d_ws, size_t ws_size,
                              hipStream_t stream) {
  const float* x1 = (const float*)d_in[0];
  const float* x2 = (const float*)d_in[1];
  double* mse_acc = (double*)d_ws;
  float* deaths   = (float*)((char*)d_ws + DEATHS_OFF);
  float* out      = (float*)d_out;

  hipMemsetAsync(d_ws, 0, 64, stream);

  int n4 = (BATCH * NPTS * DIM) / 4;
  mse_kernel<<<1024, 256, 0, stream>>>(x1, x2, mse_acc, n4);

  if (ws_size >= WS_NEED) {
    float* Dmat = (float*)((char*)d_ws + D_OFF);
    dim3 gA(NPTS / 64, NPTS / 32, NCLOUD);
    distmat_kernel<<<gA, 256, 0, stream>>>(x1, x2, Dmat);
    prim_fast<<<NCLOUD, 64, 0, stream>>>(Dmat, deaths);
    sort_kernel<<<NCLOUD, NPTS, 0, stream>>>(deaths);
  } else {
    prim_kernel<<<NCLOUD, NPTS, 0, stream>>>(x1, x2, deaths);
  }

  final_kernel<<<1, NPTS, 0, stream>>>(mse_acc, deaths, out);
}

// Round 3
// 839.043 us; speedup vs baseline: 19.1753x; 2.0340x over previous
//
#include <hip/hip_runtime.h>
#include <hip/hip_fp16.h>
#include <math.h>

#define NPTS 1024
#define DIM  128
#define BATCH 16
#define NCLOUD 32
#define BIGF 3.0e38f

// ws layout (fast path):
//   [0, 64)            : double mse_sum
//   [64, 64+128K)      : float deaths[32][1024] (later sorted in-place)
//   [196608, +64MB)    : fp16 D[32][1024][1024]
#define DEATHS_OFF 64
#define D_OFF 196608
#define WS_NEED ((size_t)D_OFF + (size_t)NCLOUD * NPTS * NPTS * 2)

__device__ __forceinline__ unsigned umin32(unsigned a, unsigned b) { return a < b ? a : b; }

// ---------------- MSE partial-sum kernel ----------------
__global__ __launch_bounds__(256) void mse_kernel(const float* __restrict__ a,
                                                  const float* __restrict__ b,
                                                  double* __restrict__ acc, int n4) {
  int i = blockIdx.x * blockDim.x + threadIdx.x;
  int stride = gridDim.x * blockDim.x;
  const float4* a4 = (const float4*)a;
  const float4* b4 = (const float4*)b;
  float s = 0.f;
  for (int k = i; k < n4; k += stride) {
    float4 va = a4[k], vb = b4[k];
    float dx = va.x - vb.x, dy = va.y - vb.y, dz = va.z - vb.z, dw = va.w - vb.w;
    s += dx * dx + dy * dy + dz * dz + dw * dw;
  }
  #pragma unroll
  for (int off = 32; off; off >>= 1) s += __shfl_xor(s, off);
  __shared__ float wsum[4];
  int lane = threadIdx.x & 63, wid = threadIdx.x >> 6;
  if (lane == 0) wsum[wid] = s;
  __syncthreads();
  if (threadIdx.x == 0)
    atomicAdd(acc, (double)(wsum[0] + wsum[1] + wsum[2] + wsum[3]));
}

// ---------------- distance-matrix kernel (fast path, fp16 output) ----------------
// Math identical to the round-1 verified f32 kernel; only the store converts to fp16.
__global__ __launch_bounds__(256) void distmat_kernel(const float* __restrict__ x1,
                                                      const float* __restrict__ x2,
                                                      unsigned short* __restrict__ Dmat) {
  const int cloud = blockIdx.z;
  const int b = cloud & (BATCH - 1);
  const int src = cloud >> 4;
  const float* xc = (src ? x2 : x1) + (size_t)b * NPTS * DIM;
  unsigned short* Dc = Dmat + ((size_t)cloud << 20);

  const int i0 = blockIdx.y * 32;
  const int j0 = blockIdx.x * 64;
  const int tid = threadIdx.x;

  __shared__ float xi_sh[32 * 132];
  __shared__ float xj_sh[64 * 32 * 4];
  __shared__ float sqi_sh[32];
  __shared__ float sqj_sh[64];

  for (int k = tid; k < 32 * 32; k += 256) {
    int r = k >> 5, c = k & 31;
    float4 v = ((const float4*)(xc + (size_t)(i0 + r) * DIM))[c];
    *((float4*)&xi_sh[r * 132 + c * 4]) = v;
  }
  for (int k = tid; k < 64 * 32; k += 256) {
    int r = k >> 5, c = k & 31;
    float4 v = ((const float4*)(xc + (size_t)(j0 + r) * DIM))[c];
    int cs = c ^ (((r >> 2) & 7) << 2);
    ((float4*)xj_sh)[r * 32 + cs] = v;
  }
  __syncthreads();

  if (tid < 32) {
    float ax = 0.f, ay = 0.f, az = 0.f, aw = 0.f;
    #pragma unroll 8
    for (int c = 0; c < 32; ++c) {
      float4 v = *((float4*)&xi_sh[tid * 132 + c * 4]);
      ax = fmaf(v.x, v.x, ax); ay = fmaf(v.y, v.y, ay);
      az = fmaf(v.z, v.z, az); aw = fmaf(v.w, v.w, aw);
    }
    sqi_sh[tid] = (ax + ay) + (az + aw);
  } else if (tid < 96) {
    int r = tid - 32;
    int sw = ((r >> 2) & 7) << 2;
    float ax = 0.f, ay = 0.f, az = 0.f, aw = 0.f;
    #pragma unroll 8
    for (int c = 0; c < 32; ++c) {
      float4 v = ((float4*)xj_sh)[r * 32 + (c ^ sw)];
      ax = fmaf(v.x, v.x, ax); ay = fmaf(v.y, v.y, ay);
      az = fmaf(v.z, v.z, az); aw = fmaf(v.w, v.w, aw);
    }
    sqj_sh[r] = (ax + ay) + (az + aw);
  }
  __syncthreads();

  const int tx = tid & 15, ty = tid >> 4;
  const int swj = (tx & 7) << 2;
  float4 acc[2][4];
  #pragma unroll
  for (int ii = 0; ii < 2; ++ii)
    #pragma unroll
    for (int jj = 0; jj < 4; ++jj)
      acc[ii][jj] = make_float4(0.f, 0.f, 0.f, 0.f);

  const float4* xi4 = (const float4*)xi_sh;
  const float4* xj4 = (const float4*)xj_sh;

  #pragma unroll 4
  for (int m = 0; m < 32; ++m) {
    float4 va[2], vb[4];
    #pragma unroll
    for (int ii = 0; ii < 2; ++ii) va[ii] = xi4[(ty * 2 + ii) * 33 + m];
    #pragma unroll
    for (int jj = 0; jj < 4; ++jj) vb[jj] = xj4[(tx * 4 + jj) * 32 + (m ^ swj)];
    #pragma unroll
    for (int ii = 0; ii < 2; ++ii)
      #pragma unroll
      for (int jj = 0; jj < 4; ++jj) {
        acc[ii][jj].x = fmaf(va[ii].x, vb[jj].x, acc[ii][jj].x);
        acc[ii][jj].y = fmaf(va[ii].y, vb[jj].y, acc[ii][jj].y);
        acc[ii][jj].z = fmaf(va[ii].z, vb[jj].z, acc[ii][jj].z);
        acc[ii][jj].w = fmaf(va[ii].w, vb[jj].w, acc[ii][jj].w);
      }
  }

  #pragma unroll
  for (int ii = 0; ii < 2; ++ii) {
    int il = ty * 2 + ii;
    int gi = i0 + il;
    unsigned short hb[4];
    #pragma unroll
    for (int jj = 0; jj < 4; ++jj) {
      int jl = tx * 4 + jj;
      int gj = j0 + jl;
      float dot = (acc[ii][jj].x + acc[ii][jj].y) + (acc[ii][jj].z + acc[ii][jj].w);
      float d2 = sqi_sh[il] + sqj_sh[jl] - 2.f * dot;
      float d = sqrtf(fmaxf(d2, 0.f) + 1e-12f);
      hb[jj] = (gi == gj) ? (unsigned short)0x7C00 : __half_as_ushort(__float2half(d));
    }
    unsigned lo = (unsigned)hb[0] | ((unsigned)hb[1] << 16);
    unsigned hi = (unsigned)hb[2] | ((unsigned)hb[3] << 16);
    *((uint2*)&Dc[(size_t)gi * NPTS + j0 + tx * 4]) = make_uint2(lo, hi);
  }
}

// ---------------- single-wave Prim on fp16 D, packed u32 keys + DPP argmin ----------------
// key = (halfbits << 16) | node_index  -> u32 min == (value, first-index) argmin, exact.
__global__ __launch_bounds__(64) void prim_fast(const unsigned short* __restrict__ Dmat,
                                                float* __restrict__ deaths_out) {
  const int cloud = blockIdx.x;
  const int lane = threadIdx.x;
  const unsigned short* Dc = Dmat + ((size_t)cloud << 20);
  const uint4* p = (const uint4*)Dc;  // 128 uint4 per row
  float* dout = deaths_out + (size_t)cloud * NPTS;

  const unsigned jl0 = (unsigned)(lane << 3);        // c=0 base index
  const unsigned jl1 = 512u + (unsigned)(lane << 3); // c=1 base index

  unsigned mind[16];
  unsigned mask = 0;

  // init: mind = keys of D row 0
  {
    uint4 ra = p[lane];
    uint4 rb = p[64 + lane];
    #define KINIT(s, w, jb) \
      mind[s]     = ((w) << 16) | ((jb));            \
      mind[(s)+1] = ((w) & 0xFFFF0000u) | ((jb) + 1);
    KINIT(0,  ra.x, jl0 + 0) KINIT(2,  ra.y, jl0 + 2)
    KINIT(4,  ra.z, jl0 + 4) KINIT(6,  ra.w, jl0 + 6)
    KINIT(8,  rb.x, jl1 + 0) KINIT(10, rb.y, jl1 + 2)
    KINIT(12, rb.z, jl1 + 4) KINIT(14, rb.w, jl1 + 6)
    #undef KINIT
    if (lane == 0) { mind[0] = 0xFFFFFFFFu; mask = 1u; }  // node 0 in tree
  }

  for (int t = 0; t < NPTS - 1; ++t) {
    // local min over 16 keys (tree; keys globally unique -> exact)
    unsigned a0 = umin32(mind[0], mind[1]),  a1 = umin32(mind[2], mind[3]);
    unsigned a2 = umin32(mind[4], mind[5]),  a3 = umin32(mind[6], mind[7]);
    unsigned a4 = umin32(mind[8], mind[9]),  a5 = umin32(mind[10], mind[11]);
    unsigned a6 = umin32(mind[12], mind[13]), a7 = umin32(mind[14], mind[15]);
    unsigned b0 = umin32(a0, a1), b1 = umin32(a2, a3);
    unsigned b2 = umin32(a4, a5), b3 = umin32(a6, a7);
    unsigned key = umin32(umin32(b0, b1), umin32(b2, b3));

    // wave64 min via DPP: row_shr 1,2,4,8 then row_bcast:15, row_bcast:31 -> lane 63
    #define DPPMIN(ctrl) { \
      unsigned tv = (unsigned)__builtin_amdgcn_update_dpp((int)key, (int)key, (ctrl), 0xF, 0xF, false); \
      key = umin32(key, tv); }
    DPPMIN(0x111) DPPMIN(0x112) DPPMIN(0x114) DPPMIN(0x118)
    DPPMIN(0x142) DPPMIN(0x143)
    #undef DPPMIN
    unsigned w = (unsigned)__builtin_amdgcn_readlane((int)key, 63);  // uniform winner

    unsigned cur = w & 0xFFFFu;
    if (lane == 0)
      dout[t] = __half2float(__ushort_as_half((unsigned short)(w >> 16)));

    // load D[cur] row (2 KB, two coalesced dwordx4 per lane)
    size_t rb4 = (size_t)cur << 7;
    uint4 ra = p[rb4 + lane];
    uint4 rbv = p[rb4 + 64 + lane];

    // mark cur in-tree on its owner lane
    if ((unsigned)lane == ((cur >> 3) & 63u))
      mask |= 1u << (((cur >> 6) & 8u) | (cur & 7u));

    // masked min-update: in-tree slots forced to ~0
    #define UPD(s, w32, jb) { \
      unsigned k0 = ((w32) << 16) | ((jb)); \
      unsigned k1 = ((w32) & 0xFFFF0000u) | ((jb) + 1); \
      unsigned t0 = umin32(mind[s], k0); \
      mind[s] = ((mask >> (s)) & 1u) ? 0xFFFFFFFFu : t0; \
      unsigned t1 = umin32(mind[(s)+1], k1); \
      mind[(s)+1] = ((mask >> ((s)+1)) & 1u) ? 0xFFFFFFFFu : t1; }
    UPD(0,  ra.x,  jl0 + 0) UPD(2,  ra.y,  jl0 + 2)
    UPD(4,  ra.z,  jl0 + 4) UPD(6,  ra.w,  jl0 + 6)
    UPD(8,  rbv.x, jl1 + 0) UPD(10, rbv.y, jl1 + 2)
    UPD(12, rbv.z, jl1 + 4) UPD(14, rbv.w, jl1 + 6)
    #undef UPD
  }

  if (lane == 0) dout[NPTS - 1] = BIGF;  // pad for power-of-2 sort
}

// ---------------- bitonic sort kernel (fast path) ----------------
__global__ __launch_bounds__(1024) void sort_kernel(float* __restrict__ buf) {
  __shared__ float s[NPTS];
  int tid = threadIdx.x;
  float* base = buf + (size_t)blockIdx.x * NPTS;
  s[tid] = base[tid];
  __syncthreads();
  for (int k = 2; k <= NPTS; k <<= 1) {
    for (int jj = k >> 1; jj > 0; jj >>= 1) {
      int i = tid;
      int l = i ^ jj;
      if (l > i) {
        float va = s[i], vb = s[l];
        bool up = ((i & k) == 0);
        if ((va > vb) == up) { s[i] = vb; s[l] = va; }
      }
      __syncthreads();
    }
  }
  base[tid] = s[tid];
}

// ---------------- fallback: round-0 fused Prim+sort (1 block / cloud) ----------------
__global__ __launch_bounds__(1024) void prim_kernel(const float* __restrict__ x1,
                                                    const float* __restrict__ x2,
                                                    float* __restrict__ sorted_out) {
  const int cloud = blockIdx.x;
  const int b = cloud & (BATCH - 1);
  const int src = cloud >> 4;
  const float* xbase = (src ? x2 : x1) + (size_t)b * NPTS * DIM;
  const int j = threadIdx.x;

  __shared__ float xi_sh[DIM];
  __shared__ float sq_sh[NPTS];
  __shared__ float redw[16];
  __shared__ int   redi[16];
  __shared__ float deaths[NPTS];

  const float4* xr = (const float4*)(xbase + (size_t)j * DIM);
  {
    float ax = 0.f, ay = 0.f, az = 0.f, aw = 0.f;
    #pragma unroll 8
    for (int m = 0; m < DIM / 4; ++m) {
      float4 v = xr[m];
      ax = fmaf(v.x, v.x, ax); ay = fmaf(v.y, v.y, ay);
      az = fmaf(v.z, v.z, az); aw = fmaf(v.w, v.w, aw);
    }
    sq_sh[j] = (ax + ay) + (az + aw);
  }
  const float sqj = sq_sh[j];

  float mind = BIGF;
  bool in_tree = (j == 0);
  int  cur = 0;

  for (int t = 0; t < NPTS - 1; ++t) {
    if (threadIdx.x < DIM / 4)
      ((float4*)xi_sh)[threadIdx.x] = ((const float4*)(xbase + (size_t)cur * DIM))[threadIdx.x];
    __syncthreads();

    const float4* xi4 = (const float4*)xi_sh;
    float ax = 0.f, ay = 0.f, az = 0.f, aw = 0.f;
    #pragma unroll 8
    for (int m = 0; m < DIM / 4; ++m) {
      float4 v = xr[m];
      float4 u = xi4[m];
      ax = fmaf(v.x, u.x, ax); ay = fmaf(v.y, u.y, ay);
      az = fmaf(v.z, u.z, az); aw = fmaf(v.w, u.w, aw);
    }
    float dot = (ax + ay) + (az + aw);
    float d2 = sq_sh[cur] + sqj - 2.f * dot;
    float d = sqrtf(fmaxf(d2, 0.f) + 1e-12f);
    mind = in_tree ? BIGF : fminf(mind, d);

    float w = mind;
    int idx = j;
    #pragma unroll
    for (int off = 32; off; off >>= 1) {
      float w2 = __shfl_xor(w, off);
      int i2 = __shfl_xor(idx, off);
      if (w2 < w || (w2 == w && i2 < idx)) { w = w2; idx = i2; }
    }
    int lane = j & 63, wid = j >> 6;
    if (lane == 0) { redw[wid] = w; redi[wid] = idx; }
    __syncthreads();

    float cw = redw[0];
    int ci = redi[0];
    #pragma unroll
    for (int q = 1; q < 16; ++q) {
      float w2 = redw[q]; int i2 = redi[q];
      if (w2 < cw || (w2 == cw && i2 < ci)) { cw = w2; ci = i2; }
    }
    if (j == ci) in_tree = true;
    if (j == 0)  deaths[t] = cw;
    cur = ci;
  }

  if (threadIdx.x == 0) deaths[NPTS - 1] = BIGF;
  __syncthreads();

  for (int k = 2; k <= NPTS; k <<= 1) {
    for (int jj = k >> 1; jj > 0; jj >>= 1) {
      int i = threadIdx.x;
      int l = i ^ jj;
      if (l > i) {
        float va = deaths[i], vb = deaths[l];
        bool up = ((i & k) == 0);
        if ((va > vb) == up) { deaths[i] = vb; deaths[l] = va; }
      }
      __syncthreads();
    }
  }
  sorted_out[(size_t)cloud * NPTS + threadIdx.x] = deaths[threadIdx.x];
}

// ---------------- final combine ----------------
__global__ __launch_bounds__(1024) void final_kernel(const double* __restrict__ mse_acc,
                                                     const float* __restrict__ sorted,
                                                     float* __restrict__ out) {
  int wid = threadIdx.x >> 6;
  int lane = threadIdx.x & 63;
  const float* s1 = sorted + (size_t)wid * NPTS;
  const float* s2 = sorted + (size_t)(BATCH + wid) * NPTS;
  float s = 0.f;
  for (int k = lane; k < NPTS; k += 64) {
    float dlt = s1[k] - s2[k];
    s += dlt * dlt;
  }
  #pragma unroll
  for (int off = 32; off; off >>= 1) s += __shfl_xor(s, off);
  __shared__ float part[16];
  if (lane == 0) part[wid] = sqrtf(s);
  __syncthreads();
  if (threadIdx.x == 0) {
    float topo = 0.f;
    #pragma unroll
    for (int q = 0; q < 16; ++q) topo += part[q];
    float mse = (float)(mse_acc[0] / (double)((size_t)BATCH * NPTS * DIM));
    out[0] = 1.0f * mse + 0.1f * topo;
  }
}

extern "C" void kernel_launch(void* const* d_in, const int* in_sizes, int n_in,
                              void* d_out, int out_size, void* d_ws, size_t ws_size,
                              hipStream_t stream) {
  const float* x1 = (const float*)d_in[0];
  const float* x2 = (const float*)d_in[1];
  double* mse_acc = (double*)d_ws;
  float* deaths   = (float*)((char*)d_ws + DEATHS_OFF);
  float* out      = (float*)d_out;

  hipMemsetAsync(d_ws, 0, 64, stream);

  int n4 = (BATCH * NPTS * DIM) / 4;
  mse_kernel<<<1024, 256, 0, stream>>>(x1, x2, mse_acc, n4);

  if (ws_size >= WS_NEED) {
    unsigned short* Dmat = (unsigned short*)((char*)d_ws + D_OFF);
    dim3 gA(NPTS / 64, NPTS / 32, NCLOUD);
    distmat_kernel<<<gA, 256, 0, stream>>>(x1, x2, Dmat);
    prim_fast<<<NCLOUD, 64, 0, stream>>>(Dmat, deaths);
    sort_kernel<<<NCLOUD, NPTS, 0, stream>>>(deaths);
  } else {
    prim_kernel<<<NCLOUD, NPTS, 0, stream>>>(x1, x2, deaths);
  }

  final_kernel<<<1, NPTS, 0, stream>>>(mse_acc, deaths, out);
}

// Round 4
// 595.305 us; speedup vs baseline: 27.0263x; 1.4094x over previous
//
#include <hip/hip_runtime.h>
#include <hip/hip_fp16.h>
#include <math.h>

#define NPTS 1024
#define DIM  128
#define BATCH 16
#define NCLOUD 32
#define BIGF 3.0e38f

// ws layout (fast path):
//   [0, 64)       : double mse_sum
//   [64, +128K)   : float deaths[32][1024] (later sorted in-place)
//   D_OFF  +64MB  : fp16 D[32][1024][1024]
//   XBF_OFF +8MB  : bf16 x[32][1024][128]
//   SQ_OFF +128KB : f32 sq[32][1024]
#define DEATHS_OFF 64
#define D_OFF 196608
#define XBF_OFF ((size_t)D_OFF + (size_t)NCLOUD * NPTS * NPTS * 2)
#define SQ_OFF  (XBF_OFF + (size_t)NCLOUD * NPTS * DIM * 2)
#define WS_NEED (SQ_OFF + (size_t)NCLOUD * NPTS * 4)

typedef __attribute__((ext_vector_type(8))) short short8;
typedef __attribute__((ext_vector_type(4))) float f32x4;

__device__ __forceinline__ unsigned umin32(unsigned a, unsigned b) { return a < b ? a : b; }

__device__ __forceinline__ unsigned bfbits(float f) {
  unsigned u = __float_as_uint(f);
  return (u + 0x7FFFu + ((u >> 16) & 1u)) >> 16;  // RNE, finite inputs
}

// ---------------- MSE partial-sum kernel ----------------
__global__ __launch_bounds__(256) void mse_kernel(const float* __restrict__ a,
                                                  const float* __restrict__ b,
                                                  double* __restrict__ acc, int n4) {
  int i = blockIdx.x * blockDim.x + threadIdx.x;
  int stride = gridDim.x * blockDim.x;
  const float4* a4 = (const float4*)a;
  const float4* b4 = (const float4*)b;
  float s = 0.f;
  for (int k = i; k < n4; k += stride) {
    float4 va = a4[k], vb = b4[k];
    float dx = va.x - vb.x, dy = va.y - vb.y, dz = va.z - vb.z, dw = va.w - vb.w;
    s += dx * dx + dy * dy + dz * dz + dw * dw;
  }
  #pragma unroll
  for (int off = 32; off; off >>= 1) s += __shfl_xor(s, off);
  __shared__ float wsum[4];
  int lane = threadIdx.x & 63, wid = threadIdx.x >> 6;
  if (lane == 0) wsum[wid] = s;
  __syncthreads();
  if (threadIdx.x == 0)
    atomicAdd(acc, (double)(wsum[0] + wsum[1] + wsum[2] + wsum[3]));
}

// ---------------- prep: f32 x -> bf16 x, plus f32 squared norms ----------------
// sq accumulation pattern bitwise-matches the previous verified kernels:
// per-float4 component accumulators, sq = (ax+ay)+(az+aw).
__global__ __launch_bounds__(256) void prep_kernel(const float* __restrict__ x1,
                                                   const float* __restrict__ x2,
                                                   unsigned short* __restrict__ xbf,
                                                   float* __restrict__ sqg) {
  const int cloud = blockIdx.x;
  const int b = cloud & (BATCH - 1);
  const int src = cloud >> 4;
  const float* xc = (src ? x2 : x1) + (size_t)b * NPTS * DIM;
  uint4* xo = (uint4*)xbf + (size_t)cloud * NPTS * (DIM / 8);
  float* sqo = sqg + (size_t)cloud * NPTS;

  for (int r = threadIdx.x; r < NPTS; r += 256) {
    const float4* xr = (const float4*)(xc + (size_t)r * DIM);
    uint4* orow = xo + (size_t)r * (DIM / 8);
    float ax = 0.f, ay = 0.f, az = 0.f, aw = 0.f;
    #pragma unroll 4
    for (int m = 0; m < 32; m += 2) {
      float4 v0 = xr[m], v1 = xr[m + 1];
      ax = fmaf(v0.x, v0.x, ax); ay = fmaf(v0.y, v0.y, ay);
      az = fmaf(v0.z, v0.z, az); aw = fmaf(v0.w, v0.w, aw);
      ax = fmaf(v1.x, v1.x, ax); ay = fmaf(v1.y, v1.y, ay);
      az = fmaf(v1.z, v1.z, az); aw = fmaf(v1.w, v1.w, aw);
      uint4 o;
      o.x = bfbits(v0.x) | (bfbits(v0.y) << 16);
      o.y = bfbits(v0.z) | (bfbits(v0.w) << 16);
      o.z = bfbits(v1.x) | (bfbits(v1.y) << 16);
      o.w = bfbits(v1.z) | (bfbits(v1.w) << 16);
      orow[m >> 1] = o;
    }
    sqo[r] = (ax + ay) + (az + aw);
  }
}

// ---------------- MFMA distance-matrix kernel ----------------
// 64x64 output tile per block (256 thr = 4 waves), bf16 16x16x32 MFMA,
// XOR-swizzled LDS (T2), f32 epilogue, fp16 store. d2 formula identical
// to previous verified kernels; only the dot is bf16-MFMA.
__global__ __launch_bounds__(256) void distmat_mfma(const unsigned short* __restrict__ xbf,
                                                    const float* __restrict__ sqg,
                                                    unsigned short* __restrict__ Dmat) {
  const int cloud = blockIdx.z;
  const int i0 = blockIdx.y * 64;
  const int j0 = blockIdx.x * 64;
  const int tid = threadIdx.x;
  const int lane = tid & 63, w = tid >> 6;

  __shared__ unsigned short Ash[64 * 128];  // 16 KB, row-major [64][128], swizzled
  __shared__ unsigned short Bsh[64 * 128];
  __shared__ float sqi_sh[64], sqj_sh[64];

  const uint4* xg = (const uint4*)xbf + (size_t)cloud * NPTS * (DIM / 8);
  uint4* A4 = (uint4*)Ash;
  uint4* B4 = (uint4*)Bsh;

  // stage: chunk c -> row = c>>4, 16B-slot c16 = c&15; swizzle slot ^= row&7
  #pragma unroll
  for (int c = tid; c < 1024; c += 256) {
    int row = c >> 4, c16 = c & 15;
    int sidx = (row << 4) | (c16 ^ (row & 7));
    A4[sidx] = xg[((size_t)(i0 + row) << 4) | c16];
    B4[sidx] = xg[((size_t)(j0 + row) << 4) | c16];
  }
  if (tid < 64) sqi_sh[tid] = sqg[(size_t)cloud * NPTS + i0 + tid];
  else if (tid < 128) sqj_sh[tid - 64] = sqg[(size_t)cloud * NPTS + j0 + tid - 64];
  __syncthreads();

  const int ar = w * 16 + (lane & 15);  // A row this lane reads (i-local)
  const int kq = lane >> 4;             // k-quarter within K=32 chunk
  f32x4 acc[4];
  #pragma unroll
  for (int jt = 0; jt < 4; ++jt) acc[jt] = (f32x4){0.f, 0.f, 0.f, 0.f};

  #pragma unroll
  for (int kk = 0; kk < 4; ++kk) {
    int acol = (kk * 4 + kq) ^ (ar & 7);
    short8 a = *(const short8*)&A4[(ar << 4) | acol];
    #pragma unroll
    for (int jt = 0; jt < 4; ++jt) {
      int br = jt * 16 + (lane & 15);  // B row (j-local); frag = 8 k-contig bf16
      int bcol = (kk * 4 + kq) ^ (br & 7);
      short8 bf = *(const short8*)&B4[(br << 4) | bcol];
      acc[jt] = __builtin_amdgcn_mfma_f32_16x16x32_bf16(a, bf, acc[jt], 0, 0, 0);
    }
  }

  unsigned short* Dc = Dmat + ((size_t)cloud << 20);
  #pragma unroll
  for (int jt = 0; jt < 4; ++jt) {
    int jl = jt * 16 + (lane & 15);
    int gj = j0 + jl;
    float sqj = sqj_sh[jl];
    #pragma unroll
    for (int r = 0; r < 4; ++r) {
      int il = w * 16 + (lane >> 4) * 4 + r;  // C/D: col=lane&15, row=(lane>>4)*4+r
      int gi = i0 + il;
      float d2 = sqi_sh[il] + sqj - 2.f * acc[jt][r];
      float d = sqrtf(fmaxf(d2, 0.f) + 1e-12f);
      unsigned short h = (gi == gj) ? (unsigned short)0x7C00 : __half_as_ushort(__float2half(d));
      Dc[(size_t)gi * NPTS + gj] = h;
    }
  }
}

// ---------------- single-wave Prim on fp16 D, packed u32 keys + DPP argmin ----------------
__global__ __launch_bounds__(64) void prim_fast(const unsigned short* __restrict__ Dmat,
                                                float* __restrict__ deaths_out) {
  const int cloud = blockIdx.x;
  const int lane = threadIdx.x;
  const unsigned short* Dc = Dmat + ((size_t)cloud << 20);
  const uint4* p = (const uint4*)Dc;  // 128 uint4 per row
  float* dout = deaths_out + (size_t)cloud * NPTS;

  const unsigned jl0 = (unsigned)(lane << 3);
  const unsigned jl1 = 512u + (unsigned)(lane << 3);

  unsigned mind[16];
  unsigned mask = 0;

  {
    uint4 ra = p[lane];
    uint4 rb = p[64 + lane];
    #define KINIT(s, w, jb) \
      mind[s]     = ((w) << 16) | ((jb));            \
      mind[(s)+1] = ((w) & 0xFFFF0000u) | ((jb) + 1);
    KINIT(0,  ra.x, jl0 + 0) KINIT(2,  ra.y, jl0 + 2)
    KINIT(4,  ra.z, jl0 + 4) KINIT(6,  ra.w, jl0 + 6)
    KINIT(8,  rb.x, jl1 + 0) KINIT(10, rb.y, jl1 + 2)
    KINIT(12, rb.z, jl1 + 4) KINIT(14, rb.w, jl1 + 6)
    #undef KINIT
    if (lane == 0) { mind[0] = 0xFFFFFFFFu; mask = 1u; }
  }

  for (int t = 0; t < NPTS - 1; ++t) {
    unsigned a0 = umin32(mind[0], mind[1]),  a1 = umin32(mind[2], mind[3]);
    unsigned a2 = umin32(mind[4], mind[5]),  a3 = umin32(mind[6], mind[7]);
    unsigned a4 = umin32(mind[8], mind[9]),  a5 = umin32(mind[10], mind[11]);
    unsigned a6 = umin32(mind[12], mind[13]), a7 = umin32(mind[14], mind[15]);
    unsigned b0 = umin32(a0, a1), b1 = umin32(a2, a3);
    unsigned b2 = umin32(a4, a5), b3 = umin32(a6, a7);
    unsigned key = umin32(umin32(b0, b1), umin32(b2, b3));

    #define DPPMIN(ctrl) { \
      unsigned tv = (unsigned)__builtin_amdgcn_update_dpp((int)key, (int)key, (ctrl), 0xF, 0xF, false); \
      key = umin32(key, tv); }
    DPPMIN(0x111) DPPMIN(0x112) DPPMIN(0x114) DPPMIN(0x118)
    DPPMIN(0x142) DPPMIN(0x143)
    #undef DPPMIN
    unsigned w = (unsigned)__builtin_amdgcn_readlane((int)key, 63);

    unsigned cur = w & 0xFFFFu;
    if (lane == 0)
      dout[t] = __half2float(__ushort_as_half((unsigned short)(w >> 16)));

    size_t rb4 = (size_t)cur << 7;
    uint4 ra = p[rb4 + lane];
    uint4 rbv = p[rb4 + 64 + lane];

    if ((unsigned)lane == ((cur >> 3) & 63u))
      mask |= 1u << (((cur >> 6) & 8u) | (cur & 7u));

    #define UPD(s, w32, jb) { \
      unsigned k0 = ((w32) << 16) | ((jb)); \
      unsigned k1 = ((w32) & 0xFFFF0000u) | ((jb) + 1); \
      unsigned t0 = umin32(mind[s], k0); \
      mind[s] = ((mask >> (s)) & 1u) ? 0xFFFFFFFFu : t0; \
      unsigned t1 = umin32(mind[(s)+1], k1); \
      mind[(s)+1] = ((mask >> ((s)+1)) & 1u) ? 0xFFFFFFFFu : t1; }
    UPD(0,  ra.x,  jl0 + 0) UPD(2,  ra.y,  jl0 + 2)
    UPD(4,  ra.z,  jl0 + 4) UPD(6,  ra.w,  jl0 + 6)
    UPD(8,  rbv.x, jl1 + 0) UPD(10, rbv.y, jl1 + 2)
    UPD(12, rbv.z, jl1 + 4) UPD(14, rbv.w, jl1 + 6)
    #undef UPD
  }

  if (lane == 0) dout[NPTS - 1] = BIGF;
}

// ---------------- bitonic sort kernel ----------------
__global__ __launch_bounds__(1024) void sort_kernel(float* __restrict__ buf) {
  __shared__ float s[NPTS];
  int tid = threadIdx.x;
  float* base = buf + (size_t)blockIdx.x * NPTS;
  s[tid] = base[tid];
  __syncthreads();
  for (int k = 2; k <= NPTS; k <<= 1) {
    for (int jj = k >> 1; jj > 0; jj >>= 1) {
      int i = tid;
      int l = i ^ jj;
      if (l > i) {
        float va = s[i], vb = s[l];
        bool up = ((i & k) == 0);
        if ((va > vb) == up) { s[i] = vb; s[l] = va; }
      }
      __syncthreads();
    }
  }
  base[tid] = s[tid];
}

// ---------------- fallback: fused Prim+sort from x (small ws) ----------------
__global__ __launch_bounds__(1024) void prim_kernel(const float* __restrict__ x1,
                                                    const float* __restrict__ x2,
                                                    float* __restrict__ sorted_out) {
  const int cloud = blockIdx.x;
  const int b = cloud & (BATCH - 1);
  const int src = cloud >> 4;
  const float* xbase = (src ? x2 : x1) + (size_t)b * NPTS * DIM;
  const int j = threadIdx.x;

  __shared__ float xi_sh[DIM];
  __shared__ float sq_sh[NPTS];
  __shared__ float redw[16];
  __shared__ int   redi[16];
  __shared__ float deaths[NPTS];

  const float4* xr = (const float4*)(xbase + (size_t)j * DIM);
  {
    float ax = 0.f, ay = 0.f, az = 0.f, aw = 0.f;
    #pragma unroll 8
    for (int m = 0; m < DIM / 4; ++m) {
      float4 v = xr[m];
      ax = fmaf(v.x, v.x, ax); ay = fmaf(v.y, v.y, ay);
      az = fmaf(v.z, v.z, az); aw = fmaf(v.w, v.w, aw);
    }
    sq_sh[j] = (ax + ay) + (az + aw);
  }
  const float sqj = sq_sh[j];

  float mind = BIGF;
  bool in_tree = (j == 0);
  int  cur = 0;

  for (int t = 0; t < NPTS - 1; ++t) {
    if (threadIdx.x < DIM / 4)
      ((float4*)xi_sh)[threadIdx.x] = ((const float4*)(xbase + (size_t)cur * DIM))[threadIdx.x];
    __syncthreads();

    const float4* xi4 = (const float4*)xi_sh;
    float ax = 0.f, ay = 0.f, az = 0.f, aw = 0.f;
    #pragma unroll 8
    for (int m = 0; m < DIM / 4; ++m) {
      float4 v = xr[m];
      float4 u = xi4[m];
      ax = fmaf(v.x, u.x, ax); ay = fmaf(v.y, u.y, ay);
      az = fmaf(v.z, u.z, az); aw = fmaf(v.w, u.w, aw);
    }
    float dot = (ax + ay) + (az + aw);
    float d2 = sq_sh[cur] + sqj - 2.f * dot;
    float d = sqrtf(fmaxf(d2, 0.f) + 1e-12f);
    mind = in_tree ? BIGF : fminf(mind, d);

    float w = mind;
    int idx = j;
    #pragma unroll
    for (int off = 32; off; off >>= 1) {
      float w2 = __shfl_xor(w, off);
      int i2 = __shfl_xor(idx, off);
      if (w2 < w || (w2 == w && i2 < idx)) { w = w2; idx = i2; }
    }
    int lane = j & 63, wid = j >> 6;
    if (lane == 0) { redw[wid] = w; redi[wid] = idx; }
    __syncthreads();

    float cw = redw[0];
    int ci = redi[0];
    #pragma unroll
    for (int q = 1; q < 16; ++q) {
      float w2 = redw[q]; int i2 = redi[q];
      if (w2 < cw || (w2 == cw && i2 < ci)) { cw = w2; ci = i2; }
    }
    if (j == ci) in_tree = true;
    if (j == 0)  deaths[t] = cw;
    cur = ci;
  }

  if (threadIdx.x == 0) deaths[NPTS - 1] = BIGF;
  __syncthreads();

  for (int k = 2; k <= NPTS; k <<= 1) {
    for (int jj = k >> 1; jj > 0; jj >>= 1) {
      int i = threadIdx.x;
      int l = i ^ jj;
      if (l > i) {
        float va = deaths[i], vb = deaths[l];
        bool up = ((i & k) == 0);
        if ((va > vb) == up) { deaths[i] = vb; deaths[l] = va; }
      }
      __syncthreads();
    }
  }
  sorted_out[(size_t)cloud * NPTS + threadIdx.x] = deaths[threadIdx.x];
}

// ---------------- final combine ----------------
__global__ __launch_bounds__(1024) void final_kernel(const double* __restrict__ mse_acc,
                                                     const float* __restrict__ sorted,
                                                     float* __restrict__ out) {
  int wid = threadIdx.x >> 6;
  int lane = threadIdx.x & 63;
  const float* s1 = sorted + (size_t)wid * NPTS;
  const float* s2 = sorted + (size_t)(BATCH + wid) * NPTS;
  float s = 0.f;
  for (int k = lane; k < NPTS; k += 64) {
    float dlt = s1[k] - s2[k];
    s += dlt * dlt;
  }
  #pragma unroll
  for (int off = 32; off; off >>= 1) s += __shfl_xor(s, off);
  __shared__ float part[16];
  if (lane == 0) part[wid] = sqrtf(s);
  __syncthreads();
  if (threadIdx.x == 0) {
    float topo = 0.f;
    #pragma unroll
    for (int q = 0; q < 16; ++q) topo += part[q];
    float mse = (float)(mse_acc[0] / (double)((size_t)BATCH * NPTS * DIM));
    out[0] = 1.0f * mse + 0.1f * topo;
  }
}

extern "C" void kernel_launch(void* const* d_in, const int* in_sizes, int n_in,
                              void* d_out, int out_size, void* d_ws, size_t ws_size,
                              hipStream_t stream) {
  const float* x1 = (const float*)d_in[0];
  const float* x2 = (const float*)d_in[1];
  double* mse_acc = (double*)d_ws;
  float* deaths   = (float*)((char*)d_ws + DEATHS_OFF);
  float* out      = (float*)d_out;

  hipMemsetAsync(d_ws, 0, 64, stream);

  int n4 = (BATCH * NPTS * DIM) / 4;
  mse_kernel<<<1024, 256, 0, stream>>>(x1, x2, mse_acc, n4);

  if (ws_size >= WS_NEED) {
    unsigned short* Dmat = (unsigned short*)((char*)d_ws + D_OFF);
    unsigned short* xbf  = (unsigned short*)((char*)d_ws + XBF_OFF);
    float* sqg           = (float*)((char*)d_ws + SQ_OFF);

    prep_kernel<<<NCLOUD, 256, 0, stream>>>(x1, x2, xbf, sqg);
    dim3 gA(NPTS / 64, NPTS / 64, NCLOUD);
    distmat_mfma<<<gA, 256, 0, stream>>>(xbf, sqg, Dmat);
    prim_fast<<<NCLOUD, 64, 0, stream>>>(Dmat, deaths);
    sort_kernel<<<NCLOUD, NPTS, 0, stream>>>(deaths);
  } else {
    prim_kernel<<<NCLOUD, NPTS, 0, stream>>>(x1, x2, deaths);
  }

  final_kernel<<<1, NPTS, 0, stream>>>(mse_acc, deaths, out);
}

// Round 5
// 242.993 us; speedup vs baseline: 66.2113x; 2.4499x over previous
//
#include <hip/hip_runtime.h>
#include <hip/hip_fp16.h>
#include <math.h>

#define NPTS 1024
#define DIM  128
#define BATCH 16
#define NCLOUD 32
#define BIGF 3.0e38f
#define BMAX 0xFFFFFFFFFFFFFFFFull

// ws layout (fast path):
//   [0, 64)       : double mse_sum
//   DEATHS_OFF    : float deaths[32][1024] (appended, then sorted in place)
//   D_OFF  +64MB  : fp16 D[32][1024][1024]
//   XBF_OFF +8MB  : bf16 x[32][1024][128]
//   SQ_OFF +128KB : f32 sq[32][1024]
//   COMP_OFF+128KB: u32 comp[32][1024]
//   BEST_OFF+256KB: u64 best[32][1024]
//   CNT_OFF +256B : u32 ncomp[32], u32 dcnt[32]
#define DEATHS_OFF 64
#define D_OFF 196608
#define XBF_OFF ((size_t)D_OFF + (size_t)NCLOUD * NPTS * NPTS * 2)
#define SQ_OFF   (XBF_OFF + (size_t)NCLOUD * NPTS * DIM * 2)
#define COMP_OFF (SQ_OFF + (size_t)NCLOUD * NPTS * 4)
#define BEST_OFF (COMP_OFF + (size_t)NCLOUD * NPTS * 4)
#define CNT_OFF  (BEST_OFF + (size_t)NCLOUD * NPTS * 8)
#define WS_NEED  (CNT_OFF + 256)

typedef __attribute__((ext_vector_type(8))) short short8;
typedef __attribute__((ext_vector_type(4))) float f32x4;

__device__ __forceinline__ unsigned umin32(unsigned a, unsigned b) { return a < b ? a : b; }

__device__ __forceinline__ unsigned bfbits(float f) {
  unsigned u = __float_as_uint(f);
  return (u + 0x7FFFu + ((u >> 16) & 1u)) >> 16;  // RNE, finite inputs
}

// ---------------- MSE partial-sum kernel ----------------
__global__ __launch_bounds__(256) void mse_kernel(const float* __restrict__ a,
                                                  const float* __restrict__ b,
                                                  double* __restrict__ acc, int n4) {
  int i = blockIdx.x * blockDim.x + threadIdx.x;
  int stride = gridDim.x * blockDim.x;
  const float4* a4 = (const float4*)a;
  const float4* b4 = (const float4*)b;
  float s = 0.f;
  for (int k = i; k < n4; k += stride) {
    float4 va = a4[k], vb = b4[k];
    float dx = va.x - vb.x, dy = va.y - vb.y, dz = va.z - vb.z, dw = va.w - vb.w;
    s += dx * dx + dy * dy + dz * dz + dw * dw;
  }
  #pragma unroll
  for (int off = 32; off; off >>= 1) s += __shfl_xor(s, off);
  __shared__ float wsum[4];
  int lane = threadIdx.x & 63, wid = threadIdx.x >> 6;
  if (lane == 0) wsum[wid] = s;
  __syncthreads();
  if (threadIdx.x == 0)
    atomicAdd(acc, (double)(wsum[0] + wsum[1] + wsum[2] + wsum[3]));
}

// ---------------- prep: f32 x -> bf16 x, f32 sq norms, Boruvka state init ----------------
__global__ __launch_bounds__(256) void prep_kernel(const float* __restrict__ x1,
                                                   const float* __restrict__ x2,
                                                   unsigned short* __restrict__ xbf,
                                                   float* __restrict__ sqg,
                                                   unsigned* __restrict__ comp,
                                                   unsigned long long* __restrict__ best,
                                                   unsigned* __restrict__ ncomp,
                                                   unsigned* __restrict__ dcnt,
                                                   float* __restrict__ deaths) {
  const int cloud = blockIdx.x;
  const int b = cloud & (BATCH - 1);
  const int src = cloud >> 4;
  const float* xc = (src ? x2 : x1) + (size_t)b * NPTS * DIM;
  uint4* xo = (uint4*)xbf + (size_t)cloud * NPTS * (DIM / 8);
  float* sqo = sqg + (size_t)cloud * NPTS;

  for (int r = threadIdx.x; r < NPTS; r += 256) {
    const float4* xr = (const float4*)(xc + (size_t)r * DIM);
    uint4* orow = xo + (size_t)r * (DIM / 8);
    float ax = 0.f, ay = 0.f, az = 0.f, aw = 0.f;
    #pragma unroll 4
    for (int m = 0; m < 32; m += 2) {
      float4 v0 = xr[m], v1 = xr[m + 1];
      ax = fmaf(v0.x, v0.x, ax); ay = fmaf(v0.y, v0.y, ay);
      az = fmaf(v0.z, v0.z, az); aw = fmaf(v0.w, v0.w, aw);
      ax = fmaf(v1.x, v1.x, ax); ay = fmaf(v1.y, v1.y, ay);
      az = fmaf(v1.z, v1.z, az); aw = fmaf(v1.w, v1.w, aw);
      uint4 o;
      o.x = bfbits(v0.x) | (bfbits(v0.y) << 16);
      o.y = bfbits(v0.z) | (bfbits(v0.w) << 16);
      o.z = bfbits(v1.x) | (bfbits(v1.y) << 16);
      o.w = bfbits(v1.z) | (bfbits(v1.w) << 16);
      orow[m >> 1] = o;
    }
    sqo[r] = (ax + ay) + (az + aw);
    comp[cloud * NPTS + r] = (unsigned)r;
    best[cloud * NPTS + r] = BMAX;
  }
  if (threadIdx.x == 0) {
    ncomp[cloud] = NPTS;
    dcnt[cloud] = 0;
    deaths[(size_t)cloud * NPTS + NPTS - 1] = BIGF;  // sort pad
  }
}

// ---------------- MFMA distance-matrix kernel (verified round 3) ----------------
__global__ __launch_bounds__(256) void distmat_mfma(const unsigned short* __restrict__ xbf,
                                                    const float* __restrict__ sqg,
                                                    unsigned short* __restrict__ Dmat) {
  const int cloud = blockIdx.z;
  const int i0 = blockIdx.y * 64;
  const int j0 = blockIdx.x * 64;
  const int tid = threadIdx.x;
  const int lane = tid & 63, w = tid >> 6;

  __shared__ unsigned short Ash[64 * 128];
  __shared__ unsigned short Bsh[64 * 128];
  __shared__ float sqi_sh[64], sqj_sh[64];

  const uint4* xg = (const uint4*)xbf + (size_t)cloud * NPTS * (DIM / 8);
  uint4* A4 = (uint4*)Ash;
  uint4* B4 = (uint4*)Bsh;

  #pragma unroll
  for (int c = tid; c < 1024; c += 256) {
    int row = c >> 4, c16 = c & 15;
    int sidx = (row << 4) | (c16 ^ (row & 7));
    A4[sidx] = xg[((size_t)(i0 + row) << 4) | c16];
    B4[sidx] = xg[((size_t)(j0 + row) << 4) | c16];
  }
  if (tid < 64) sqi_sh[tid] = sqg[(size_t)cloud * NPTS + i0 + tid];
  else if (tid < 128) sqj_sh[tid - 64] = sqg[(size_t)cloud * NPTS + j0 + tid - 64];
  __syncthreads();

  const int ar = w * 16 + (lane & 15);
  const int kq = lane >> 4;
  f32x4 acc[4];
  #pragma unroll
  for (int jt = 0; jt < 4; ++jt) acc[jt] = (f32x4){0.f, 0.f, 0.f, 0.f};

  #pragma unroll
  for (int kk = 0; kk < 4; ++kk) {
    int acol = (kk * 4 + kq) ^ (ar & 7);
    short8 a = *(const short8*)&A4[(ar << 4) | acol];
    #pragma unroll
    for (int jt = 0; jt < 4; ++jt) {
      int br = jt * 16 + (lane & 15);
      int bcol = (kk * 4 + kq) ^ (br & 7);
      short8 bf = *(const short8*)&B4[(br << 4) | bcol];
      acc[jt] = __builtin_amdgcn_mfma_f32_16x16x32_bf16(a, bf, acc[jt], 0, 0, 0);
    }
  }

  unsigned short* Dc = Dmat + ((size_t)cloud << 20);
  #pragma unroll
  for (int jt = 0; jt < 4; ++jt) {
    int jl = jt * 16 + (lane & 15);
    int gj = j0 + jl;
    float sqj = sqj_sh[jl];
    #pragma unroll
    for (int r = 0; r < 4; ++r) {
      int il = w * 16 + (lane >> 4) * 4 + r;
      int gi = i0 + il;
      float d2 = sqi_sh[il] + sqj - 2.f * acc[jt][r];
      float d = sqrtf(fmaxf(d2, 0.f) + 1e-12f);
      unsigned short h = (gi == gj) ? (unsigned short)0x7C00 : __half_as_ushort(__float2half(d));
      Dc[(size_t)gi * NPTS + gj] = h;
    }
  }
}

// ---------------- Boruvka round 1: per-row masked min -> per-component atomicMin ----------------
// grid (8, NCLOUD); block 256 = 4 waves; each wave scans 32 rows.
// row key32 = (halfbits<<16) | j ; component key64 = (w<<20)|(cmin<<10)|cmax (globally unique).
__global__ __launch_bounds__(256) void boruvka_scan(const unsigned short* __restrict__ Dmat,
                                                    const unsigned* __restrict__ comp,
                                                    unsigned long long* __restrict__ best,
                                                    const unsigned* __restrict__ ncomp) {
  const int cloud = blockIdx.y;
  if (ncomp[cloud] == 1) return;
  const int lane = threadIdx.x & 63;
  const int wid = threadIdx.x >> 6;

  __shared__ unsigned short comp16[NPTS];
  const unsigned* compc = comp + cloud * NPTS;
  for (int i = threadIdx.x; i < NPTS; i += 256) comp16[i] = (unsigned short)compc[i];
  __syncthreads();

  // per-lane component ids of the 16 owned columns (hoisted out of the row loop)
  unsigned cj[16];
  #pragma unroll
  for (int e = 0; e < 8; ++e) cj[e] = comp16[(lane << 3) + e];
  #pragma unroll
  for (int e = 0; e < 8; ++e) cj[8 + e] = comp16[512 + (lane << 3) + e];

  const uint4* p = (const uint4*)(Dmat + ((size_t)cloud << 20));
  unsigned long long* bestc = best + cloud * NPTS;
  const unsigned jb0 = (unsigned)(lane << 3), jb1 = 512u + jb0;

  const int row0 = blockIdx.x * 128 + wid * 32;
  for (int rr = 0; rr < 32; ++rr) {
    int row = row0 + rr;
    unsigned ci = (unsigned)comp16[row];  // LDS broadcast
    uint4 ra = p[row * 128 + lane];
    uint4 rb = p[row * 128 + 64 + lane];
    unsigned key = 0xFFFFFFFFu;
    #define ENT(word, cl, ch, jb) { \
      unsigned klo = ((word) << 16) | (jb); \
      unsigned khi = ((word) & 0xFFFF0000u) | ((jb) + 1); \
      key = umin32(key, (cl) == ci ? 0xFFFFFFFFu : klo); \
      key = umin32(key, (ch) == ci ? 0xFFFFFFFFu : khi); }
    ENT(ra.x, cj[0],  cj[1],  jb0 + 0) ENT(ra.y, cj[2],  cj[3],  jb0 + 2)
    ENT(ra.z, cj[4],  cj[5],  jb0 + 4) ENT(ra.w, cj[6],  cj[7],  jb0 + 6)
    ENT(rb.x, cj[8],  cj[9],  jb1 + 0) ENT(rb.y, cj[10], cj[11], jb1 + 2)
    ENT(rb.z, cj[12], cj[13], jb1 + 4) ENT(rb.w, cj[14], cj[15], jb1 + 6)
    #undef ENT

    #define DPPMIN(ctrl) { \
      unsigned tv = (unsigned)__builtin_amdgcn_update_dpp((int)key, (int)key, (ctrl), 0xF, 0xF, false); \
      key = umin32(key, tv); }
    DPPMIN(0x111) DPPMIN(0x112) DPPMIN(0x114) DPPMIN(0x118)
    DPPMIN(0x142) DPPMIN(0x143)
    #undef DPPMIN

    if (lane == 63 && key != 0xFFFFFFFFu) {  // lane 63 holds the row min
      unsigned wv = key >> 16, v = key & 0xFFFFu;
      unsigned cmin = umin32((unsigned)row, v);
      unsigned cmax = (unsigned)row + v - cmin;
      unsigned long long k64 =
          ((unsigned long long)wv << 20) | (unsigned long long)((cmin << 10) | cmax);
      atomicMin(&bestc[ci], k64);
    }
  }
}

// ---------------- Boruvka round 2: hook, 2-cycle break, append deaths, pointer-jump ----------------
__global__ __launch_bounds__(1024) void boruvka_merge(unsigned* __restrict__ comp,
                                                      unsigned long long* __restrict__ best,
                                                      unsigned* __restrict__ ncomp,
                                                      unsigned* __restrict__ dcnt,
                                                      float* __restrict__ deaths) {
  const int cloud = blockIdx.x;
  if (ncomp[cloud] == 1) return;
  const int i = threadIdx.x;
  unsigned* compc = comp + cloud * NPTS;
  unsigned long long* bestc = best + cloud * NPTS;

  __shared__ unsigned short c16[NPTS];
  __shared__ unsigned short par[NPTS];
  __shared__ unsigned cnt_sh;

  unsigned cold = compc[i];
  c16[i] = (unsigned short)cold;
  par[i] = (unsigned short)i;
  unsigned long long bk = bestc[i];
  __syncthreads();

  bool isroot = (cold == (unsigned)i);
  unsigned partner = (unsigned)i;
  unsigned wbits = 0;
  if (isroot && bk != BMAX) {
    wbits = (unsigned)(bk >> 20) & 0xFFFFu;
    unsigned cmin = (unsigned)(bk >> 10) & 1023u;
    unsigned cmax = (unsigned)bk & 1023u;
    unsigned ca = c16[cmin], cb = c16[cmax];
    partner = (ca == (unsigned)i) ? cb : ca;
    par[i] = (unsigned short)partner;
  }
  __syncthreads();
  unsigned pp = par[partner];
  bool twoc = (partner != (unsigned)i) && (pp == (unsigned)i);
  bool winner = twoc && ((unsigned)i < partner);
  bool append = (partner != (unsigned)i) && !winner;
  __syncthreads();
  if (winner) par[i] = (unsigned short)i;
  if (append) {
    unsigned slot = atomicAdd(&dcnt[cloud], 1u);
    deaths[(size_t)cloud * NPTS + slot] = __half2float(__ushort_as_half((unsigned short)wbits));
  }
  __syncthreads();
  #pragma unroll
  for (int it = 0; it < 10; ++it) {
    unsigned np = par[par[i]];
    __syncthreads();
    par[i] = (unsigned short)np;
    __syncthreads();
  }
  unsigned newc = par[cold];
  compc[i] = newc;
  if (i == 0) cnt_sh = 0;
  __syncthreads();
  unsigned long long isr = __ballot(newc == (unsigned)i);
  if ((i & 63) == 0) atomicAdd(&cnt_sh, (unsigned)__popcll(isr));
  __syncthreads();
  if (i == 0) ncomp[cloud] = cnt_sh;
  bestc[i] = BMAX;
}

// ---------------- bitonic sort kernel ----------------
__global__ __launch_bounds__(1024) void sort_kernel(float* __restrict__ buf) {
  __shared__ float s[NPTS];
  int tid = threadIdx.x;
  float* base = buf + (size_t)blockIdx.x * NPTS;
  s[tid] = base[tid];
  __syncthreads();
  for (int k = 2; k <= NPTS; k <<= 1) {
    for (int jj = k >> 1; jj > 0; jj >>= 1) {
      int i = tid;
      int l = i ^ jj;
      if (l > i) {
        float va = s[i], vb = s[l];
        bool up = ((i & k) == 0);
        if ((va > vb) == up) { s[i] = vb; s[l] = va; }
      }
      __syncthreads();
    }
  }
  base[tid] = s[tid];
}

// ---------------- fallback: fused Prim+sort from x (small ws) ----------------
__global__ __launch_bounds__(1024) void prim_kernel(const float* __restrict__ x1,
                                                    const float* __restrict__ x2,
                                                    float* __restrict__ sorted_out) {
  const int cloud = blockIdx.x;
  const int b = cloud & (BATCH - 1);
  const int src = cloud >> 4;
  const float* xbase = (src ? x2 : x1) + (size_t)b * NPTS * DIM;
  const int j = threadIdx.x;

  __shared__ float xi_sh[DIM];
  __shared__ float sq_sh[NPTS];
  __shared__ float redw[16];
  __shared__ int   redi[16];
  __shared__ float deaths[NPTS];

  const float4* xr = (const float4*)(xbase + (size_t)j * DIM);
  {
    float ax = 0.f, ay = 0.f, az = 0.f, aw = 0.f;
    #pragma unroll 8
    for (int m = 0; m < DIM / 4; ++m) {
      float4 v = xr[m];
      ax = fmaf(v.x, v.x, ax); ay = fmaf(v.y, v.y, ay);
      az = fmaf(v.z, v.z, az); aw = fmaf(v.w, v.w, aw);
    }
    sq_sh[j] = (ax + ay) + (az + aw);
  }
  const float sqj = sq_sh[j];

  float mind = BIGF;
  bool in_tree = (j == 0);
  int  cur = 0;

  for (int t = 0; t < NPTS - 1; ++t) {
    if (threadIdx.x < DIM / 4)
      ((float4*)xi_sh)[threadIdx.x] = ((const float4*)(xbase + (size_t)cur * DIM))[threadIdx.x];
    __syncthreads();

    const float4* xi4 = (const float4*)xi_sh;
    float ax = 0.f, ay = 0.f, az = 0.f, aw = 0.f;
    #pragma unroll 8
    for (int m = 0; m < DIM / 4; ++m) {
      float4 v = xr[m];
      float4 u = xi4[m];
      ax = fmaf(v.x, u.x, ax); ay = fmaf(v.y, u.y, ay);
      az = fmaf(v.z, u.z, az); aw = fmaf(v.w, u.w, aw);
    }
    float dot = (ax + ay) + (az + aw);
    float d2 = sq_sh[cur] + sqj - 2.f * dot;
    float d = sqrtf(fmaxf(d2, 0.f) + 1e-12f);
    mind = in_tree ? BIGF : fminf(mind, d);

    float w = mind;
    int idx = j;
    #pragma unroll
    for (int off = 32; off; off >>= 1) {
      float w2 = __shfl_xor(w, off);
      int i2 = __shfl_xor(idx, off);
      if (w2 < w || (w2 == w && i2 < idx)) { w = w2; idx = i2; }
    }
    int lane = j & 63, wid = j >> 6;
    if (lane == 0) { redw[wid] = w; redi[wid] = idx; }
    __syncthreads();

    float cw = redw[0];
    int ci = redi[0];
    #pragma unroll
    for (int q = 1; q < 16; ++q) {
      float w2 = redw[q]; int i2 = redi[q];
      if (w2 < cw || (w2 == cw && i2 < ci)) { cw = w2; ci = i2; }
    }
    if (j == ci) in_tree = true;
    if (j == 0)  deaths[t] = cw;
    cur = ci;
  }

  if (threadIdx.x == 0) deaths[NPTS - 1] = BIGF;
  __syncthreads();

  for (int k = 2; k <= NPTS; k <<= 1) {
    for (int jj = k >> 1; jj > 0; jj >>= 1) {
      int i = threadIdx.x;
      int l = i ^ jj;
      if (l > i) {
        float va = deaths[i], vb = deaths[l];
        bool up = ((i & k) == 0);
        if ((va > vb) == up) { deaths[i] = vb; deaths[l] = va; }
      }
      __syncthreads();
    }
  }
  sorted_out[(size_t)cloud * NPTS + threadIdx.x] = deaths[threadIdx.x];
}

// ---------------- final combine ----------------
__global__ __launch_bounds__(1024) void final_kernel(const double* __restrict__ mse_acc,
                                                     const float* __restrict__ sorted,
                                                     float* __restrict__ out) {
  int wid = threadIdx.x >> 6;
  int lane = threadIdx.x & 63;
  const float* s1 = sorted + (size_t)wid * NPTS;
  const float* s2 = sorted + (size_t)(BATCH + wid) * NPTS;
  float s = 0.f;
  for (int k = lane; k < NPTS; k += 64) {
    float dlt = s1[k] - s2[k];
    s += dlt * dlt;
  }
  #pragma unroll
  for (int off = 32; off; off >>= 1) s += __shfl_xor(s, off);
  __shared__ float part[16];
  if (lane == 0) part[wid] = sqrtf(s);
  __syncthreads();
  if (threadIdx.x == 0) {
    float topo = 0.f;
    #pragma unroll
    for (int q = 0; q < 16; ++q) topo += part[q];
    float mse = (float)(mse_acc[0] / (double)((size_t)BATCH * NPTS * DIM));
    out[0] = 1.0f * mse + 0.1f * topo;
  }
}

extern "C" void kernel_launch(void* const* d_in, const int* in_sizes, int n_in,
                              void* d_out, int out_size, void* d_ws, size_t ws_size,
                              hipStream_t stream) {
  const float* x1 = (const float*)d_in[0];
  const float* x2 = (const float*)d_in[1];
  double* mse_acc = (double*)d_ws;
  float* deaths   = (float*)((char*)d_ws + DEATHS_OFF);
  float* out      = (float*)d_out;

  hipMemsetAsync(d_ws, 0, 64, stream);

  int n4 = (BATCH * NPTS * DIM) / 4;
  mse_kernel<<<1024, 256, 0, stream>>>(x1, x2, mse_acc, n4);

  if (ws_size >= WS_NEED) {
    unsigned short* Dmat = (unsigned short*)((char*)d_ws + D_OFF);
    unsigned short* xbf  = (unsigned short*)((char*)d_ws + XBF_OFF);
    float* sqg           = (float*)((char*)d_ws + SQ_OFF);
    unsigned* comp       = (unsigned*)((char*)d_ws + COMP_OFF);
    unsigned long long* best = (unsigned long long*)((char*)d_ws + BEST_OFF);
    unsigned* ncomp      = (unsigned*)((char*)d_ws + CNT_OFF);
    unsigned* dcnt       = ncomp + NCLOUD;

    prep_kernel<<<NCLOUD, 256, 0, stream>>>(x1, x2, xbf, sqg, comp, best, ncomp, dcnt, deaths);
    dim3 gA(NPTS / 64, NPTS / 64, NCLOUD);
    distmat_mfma<<<gA, 256, 0, stream>>>(xbf, sqg, Dmat);

    for (int round = 0; round < 10; ++round) {
      boruvka_scan<<<dim3(8, NCLOUD), 256, 0, stream>>>(Dmat, comp, best, ncomp);
      boruvka_merge<<<NCLOUD, 1024, 0, stream>>>(comp, best, ncomp, dcnt, deaths);
    }
    sort_kernel<<<NCLOUD, NPTS, 0, stream>>>(deaths);
  } else {
    prim_kernel<<<NCLOUD, NPTS, 0, stream>>>(x1, x2, deaths);
  }

  final_kernel<<<1, NPTS, 0, stream>>>(mse_acc, deaths, out);
}

// Round 6
// 226.216 us; speedup vs baseline: 71.1219x; 1.0742x over previous
//
#include <hip/hip_runtime.h>
#include <hip/hip_fp16.h>
#include <math.h>

#define NPTS 1024
#define DIM  128
#define BATCH 16
#define NCLOUD 32
#define BIGF 3.0e38f
#define BMAX 0xFFFFFFFFFFFFFFFFull
#define NROUNDS 9

// ws layout (fast path):
//   [0, 64)       : double mse_sum
//   DEATHS_OFF    : float deaths[32][1024] (appended, then sorted in place)
//   D_OFF  +64MB  : fp16 D[32][1024][1024]
//   XBF_OFF +8MB  : bf16 x[32][1024][128]
//   SQ_OFF +128KB : f32 sq[32][1024]
//   COMP_OFF      : u32 comp[32][1024]
//   BEST_OFF      : u64 best[32][1024]
//   CNT_OFF       : u32 ncomp[32], u32 dcnt[32]
//   TICK_OFF      : u32 tickets[NROUNDS][32]
#define DEATHS_OFF 64
#define D_OFF 196608
#define XBF_OFF ((size_t)D_OFF + (size_t)NCLOUD * NPTS * NPTS * 2)
#define SQ_OFF   (XBF_OFF + (size_t)NCLOUD * NPTS * DIM * 2)
#define COMP_OFF (SQ_OFF + (size_t)NCLOUD * NPTS * 4)
#define BEST_OFF (COMP_OFF + (size_t)NCLOUD * NPTS * 4)
#define CNT_OFF  (BEST_OFF + (size_t)NCLOUD * NPTS * 8)
#define TICK_OFF (CNT_OFF + 256)
#define WS_NEED  (TICK_OFF + 4096)

typedef __attribute__((ext_vector_type(8))) short short8;
typedef __attribute__((ext_vector_type(4))) float f32x4;

__device__ __forceinline__ unsigned umin32(unsigned a, unsigned b) { return a < b ? a : b; }

__device__ __forceinline__ unsigned bfbits(float f) {
  unsigned u = __float_as_uint(f);
  return (u + 0x7FFFu + ((u >> 16) & 1u)) >> 16;  // RNE, finite inputs
}

// ---------------- fused prep + MSE + state init ----------------
// grid (16 batches, 8 slices) x 256 thr. Threads 0-127: x1 rows (+ MSE),
// threads 128-255: x2 rows. sq accumulation bitwise-matches prior kernels.
__global__ __launch_bounds__(256) void prep_mse(const float* __restrict__ x1,
                                                const float* __restrict__ x2,
                                                unsigned short* __restrict__ xbf,
                                                float* __restrict__ sqg,
                                                unsigned* __restrict__ comp,
                                                unsigned long long* __restrict__ best,
                                                unsigned* __restrict__ ncomp,
                                                unsigned* __restrict__ dcnt,
                                                float* __restrict__ deaths,
                                                unsigned* __restrict__ tickets,
                                                double* __restrict__ acc) {
  const int b = blockIdx.x;
  const int s = blockIdx.y;
  const int tid = threadIdx.x;

  if (s == 0 && tid == 0) {
    ncomp[b] = NPTS; ncomp[16 + b] = NPTS;
    dcnt[b] = 0; dcnt[16 + b] = 0;
    deaths[(size_t)b * NPTS + NPTS - 1] = BIGF;
    deaths[(size_t)(16 + b) * NPTS + NPTS - 1] = BIGF;
  }
  if (b == 0 && s == 0)
    for (int t = tid; t < NROUNDS * NCLOUD; t += 256) tickets[t] = 0;

  const int half = tid >> 7;
  const int r = s * 128 + (tid & 127);
  const int cloud = half * 16 + b;
  const float* xc = (half ? x2 : x1) + (size_t)b * NPTS * DIM;
  const float4* xr = (const float4*)(xc + (size_t)r * DIM);
  const float4* yr = (const float4*)(x2 + (size_t)b * NPTS * DIM + (size_t)r * DIM);
  uint4* orow = (uint4*)xbf + (size_t)cloud * NPTS * (DIM / 8) + (size_t)r * (DIM / 8);

  float mse_s = 0.f;
  float ax = 0.f, ay = 0.f, az = 0.f, aw = 0.f;
  #pragma unroll 4
  for (int m = 0; m < 32; m += 2) {
    float4 v0 = xr[m], v1 = xr[m + 1];
    ax = fmaf(v0.x, v0.x, ax); ay = fmaf(v0.y, v0.y, ay);
    az = fmaf(v0.z, v0.z, az); aw = fmaf(v0.w, v0.w, aw);
    ax = fmaf(v1.x, v1.x, ax); ay = fmaf(v1.y, v1.y, ay);
    az = fmaf(v1.z, v1.z, az); aw = fmaf(v1.w, v1.w, aw);
    uint4 o;
    o.x = bfbits(v0.x) | (bfbits(v0.y) << 16);
    o.y = bfbits(v0.z) | (bfbits(v0.w) << 16);
    o.z = bfbits(v1.x) | (bfbits(v1.y) << 16);
    o.w = bfbits(v1.z) | (bfbits(v1.w) << 16);
    orow[m >> 1] = o;
    if (half == 0) {
      float4 u0 = yr[m], u1 = yr[m + 1];
      float d0 = v0.x - u0.x, d1 = v0.y - u0.y, d2 = v0.z - u0.z, d3 = v0.w - u0.w;
      float e0 = v1.x - u1.x, e1 = v1.y - u1.y, e2 = v1.z - u1.z, e3 = v1.w - u1.w;
      mse_s += d0 * d0 + d1 * d1 + d2 * d2 + d3 * d3;
      mse_s += e0 * e0 + e1 * e1 + e2 * e2 + e3 * e3;
    }
  }
  sqg[cloud * NPTS + r] = (ax + ay) + (az + aw);
  comp[cloud * NPTS + r] = (unsigned)r;
  best[cloud * NPTS + r] = BMAX;

  #pragma unroll
  for (int off = 32; off; off >>= 1) mse_s += __shfl_xor(mse_s, off);
  __shared__ float wsum[4];
  int lane = tid & 63, wid = tid >> 6;
  if (lane == 0) wsum[wid] = mse_s;
  __syncthreads();
  if (tid == 0)
    atomicAdd(acc, (double)(wsum[0] + wsum[1] + wsum[2] + wsum[3]));
}

// ---------------- MFMA distance matrix, 128x128 tile + fused Boruvka round-1 ----
// 4 waves, each a 64x64 register tile (4x4 16x16x32 MFMA frags). Transposed
// packed store (D symmetric, bitwise): D[gj][gi0..gi0+3] as uint2.
__global__ __launch_bounds__(256) void distmat_mfma(const unsigned short* __restrict__ xbf,
                                                    const float* __restrict__ sqg,
                                                    unsigned short* __restrict__ Dmat,
                                                    unsigned long long* __restrict__ best) {
  const int cloud = blockIdx.z;
  const int i0 = blockIdx.y * 128;
  const int j0 = blockIdx.x * 128;
  const int tid = threadIdx.x;
  const int lane = tid & 63, w = tid >> 6;
  const int rw = w >> 1, cw = w & 1;
  const int l15 = lane & 15, kq = lane >> 4;

  __shared__ unsigned short Ash[128 * 128];  // 32 KB (swizzled 16B chunks)
  __shared__ unsigned short Bsh[128 * 128];  // 32 KB -> exactly 64 KB total

  const uint4* xg = (const uint4*)xbf + (size_t)cloud * NPTS * (DIM / 8);
  uint4* A4 = (uint4*)Ash;
  uint4* B4 = (uint4*)Bsh;

  #pragma unroll
  for (int c = tid; c < 2048; c += 256) {
    int row = c >> 4, c16 = c & 15;
    int sidx = (row << 4) | (c16 ^ (row & 7));
    A4[sidx] = xg[((size_t)(i0 + row) << 4) | c16];
    B4[sidx] = xg[((size_t)(j0 + row) << 4) | c16];
  }
  __syncthreads();

  f32x4 acc[4][4];
  #pragma unroll
  for (int ai = 0; ai < 4; ++ai)
    #pragma unroll
    for (int bj = 0; bj < 4; ++bj) acc[ai][bj] = (f32x4){0.f, 0.f, 0.f, 0.f};

  #pragma unroll
  for (int kk = 0; kk < 4; ++kk) {
    short8 av[4], bv[4];
    #pragma unroll
    for (int ai = 0; ai < 4; ++ai) {
      int ar = rw * 64 + ai * 16 + l15;
      int acol = (kk * 4 + kq) ^ (ar & 7);
      av[ai] = *(const short8*)&A4[(ar << 4) | acol];
    }
    #pragma unroll
    for (int bj = 0; bj < 4; ++bj) {
      int br = cw * 64 + bj * 16 + l15;
      int bcol = (kk * 4 + kq) ^ (br & 7);
      bv[bj] = *(const short8*)&B4[(br << 4) | bcol];
    }
    #pragma unroll
    for (int ai = 0; ai < 4; ++ai)
      #pragma unroll
      for (int bj = 0; bj < 4; ++bj)
        acc[ai][bj] = __builtin_amdgcn_mfma_f32_16x16x32_bf16(av[ai], bv[bj], acc[ai][bj], 0, 0, 0);
  }

  unsigned short* Dc = Dmat + ((size_t)cloud << 20);
  unsigned long long* bestc = best + cloud * NPTS;
  const float* sqc = sqg + cloud * NPTS;

  float sqjv[4]; int gjv[4];
  #pragma unroll
  for (int bj = 0; bj < 4; ++bj) {
    gjv[bj] = j0 + cw * 64 + bj * 16 + l15;
    sqjv[bj] = sqc[gjv[bj]];
  }

  unsigned kmin[4][4];  // [ai][r] row-min keys (h<<16)|gj
  #pragma unroll
  for (int ai = 0; ai < 4; ++ai)
    #pragma unroll
    for (int r = 0; r < 4; ++r) kmin[ai][r] = 0xFFFFFFFFu;

  #pragma unroll
  for (int ai = 0; ai < 4; ++ai) {
    int gib = i0 + rw * 64 + ai * 16 + (lane >> 4) * 4;
    float sqi0 = sqc[gib + 0], sqi1 = sqc[gib + 1];
    float sqi2 = sqc[gib + 2], sqi3 = sqc[gib + 3];
    #pragma unroll
    for (int bj = 0; bj < 4; ++bj) {
      unsigned hh[4];
      float sqiv[4] = {sqi0, sqi1, sqi2, sqi3};
      #pragma unroll
      for (int r = 0; r < 4; ++r) {
        int gi = gib + r;
        float d2 = sqiv[r] + sqjv[bj] - 2.f * acc[ai][bj][r];
        float d = sqrtf(fmaxf(d2, 0.f) + 1e-12f);
        unsigned h = (gi == gjv[bj]) ? 0x7C00u : (unsigned)__half_as_ushort(__float2half(d));
        hh[r] = h;
        kmin[ai][r] = umin32(kmin[ai][r], (h << 16) | (unsigned)gjv[bj]);
      }
      // transposed packed store: D[gj][gib..gib+3] (D symmetric, bitwise)
      *(uint2*)&Dc[((size_t)gjv[bj] << 10) + gib] =
          make_uint2(hh[0] | (hh[1] << 16), hh[2] | (hh[3] << 16));
    }
  }

  // round-1 best: reduce row-min over the 16-lane col group, atomicMin per row
  #pragma unroll
  for (int ai = 0; ai < 4; ++ai)
    #pragma unroll
    for (int r = 0; r < 4; ++r) {
      unsigned k = kmin[ai][r];
      k = umin32(k, __shfl_xor(k, 1));
      k = umin32(k, __shfl_xor(k, 2));
      k = umin32(k, __shfl_xor(k, 4));
      k = umin32(k, __shfl_xor(k, 8));
      if (l15 == 0) {
        unsigned gi = (unsigned)(i0 + rw * 64 + ai * 16 + (lane >> 4) * 4 + r);
        unsigned j = k & 0xFFFFu, hv = k >> 16;
        unsigned cmn = umin32(gi, j);
        unsigned cmx = gi + j - cmn;
        unsigned long long k64 =
            ((unsigned long long)hv << 20) | (unsigned long long)((cmn << 10) | cmx);
        atomicMin(&bestc[gi], k64);
      }
    }
}

// ---------------- standalone merge (round 1), 1024 thr / cloud ----------------
__global__ __launch_bounds__(1024) void boruvka_merge(unsigned* __restrict__ comp,
                                                      unsigned long long* __restrict__ best,
                                                      unsigned* __restrict__ ncomp,
                                                      unsigned* __restrict__ dcnt,
                                                      float* __restrict__ deaths) {
  const int cloud = blockIdx.x;
  if (ncomp[cloud] == 1) return;
  const int i = threadIdx.x;
  unsigned* compc = comp + cloud * NPTS;
  unsigned long long* bestc = best + cloud * NPTS;

  __shared__ unsigned short c16[NPTS];
  __shared__ unsigned short par[NPTS];
  __shared__ unsigned cnt_sh;

  unsigned cold = compc[i];
  c16[i] = (unsigned short)cold;
  par[i] = (unsigned short)i;
  unsigned long long bk = bestc[i];
  __syncthreads();

  bool isroot = (cold == (unsigned)i);
  unsigned partner = (unsigned)i;
  unsigned wbits = 0;
  if (isroot && bk != BMAX) {
    wbits = (unsigned)(bk >> 20) & 0xFFFFu;
    unsigned cmin = (unsigned)(bk >> 10) & 1023u;
    unsigned cmax = (unsigned)bk & 1023u;
    unsigned ca = c16[cmin], cb = c16[cmax];
    partner = (ca == (unsigned)i) ? cb : ca;
    par[i] = (unsigned short)partner;
  }
  __syncthreads();
  unsigned pp = par[partner];
  bool twoc = (partner != (unsigned)i) && (pp == (unsigned)i);
  bool winner = twoc && ((unsigned)i < partner);
  bool append = (partner != (unsigned)i) && !winner;
  __syncthreads();
  if (winner) par[i] = (unsigned short)i;
  if (append) {
    unsigned slot = atomicAdd(&dcnt[cloud], 1u);
    deaths[(size_t)cloud * NPTS + slot] = __half2float(__ushort_as_half((unsigned short)wbits));
  }
  __syncthreads();
  #pragma unroll
  for (int it = 0; it < 10; ++it) {
    unsigned np = par[par[i]];
    __syncthreads();
    par[i] = (unsigned short)np;
    __syncthreads();
  }
  unsigned newc = par[cold];
  compc[i] = newc;
  if (i == 0) cnt_sh = 0;
  __syncthreads();
  unsigned long long isr = __ballot(newc == (unsigned)i);
  if ((i & 63) == 0) atomicAdd(&cnt_sh, (unsigned)__popcll(isr));
  __syncthreads();
  if (i == 0) ncomp[cloud] = cnt_sh;
  bestc[i] = BMAX;
}

// ---------------- fused Boruvka round: scan + (last block) merge ----------------
// grid (8, NCLOUD) x 256 thr. Last-arriving block of a cloud (device ticket)
// runs the merge inline; best[] read back via atomicMin(p,BMAX) (L2-coherent).
__global__ __launch_bounds__(256) void boruvka_round(const unsigned short* __restrict__ Dmat,
                                                     unsigned* __restrict__ comp,
                                                     unsigned long long* __restrict__ best,
                                                     unsigned* __restrict__ ncomp,
                                                     unsigned* __restrict__ dcnt,
                                                     float* __restrict__ deaths,
                                                     unsigned* __restrict__ ticket) {
  const int cloud = blockIdx.y;
  if (ncomp[cloud] == 1) return;
  const int tid = threadIdx.x;
  const int lane = tid & 63, wid = tid >> 6;

  __shared__ unsigned short comp16[NPTS];
  unsigned* compc = comp + cloud * NPTS;
  for (int i = tid; i < NPTS; i += 256) comp16[i] = (unsigned short)compc[i];
  __syncthreads();

  // ---- scan phase ----
  unsigned cj[16];
  #pragma unroll
  for (int e = 0; e < 8; ++e) cj[e] = comp16[(lane << 3) + e];
  #pragma unroll
  for (int e = 0; e < 8; ++e) cj[8 + e] = comp16[512 + (lane << 3) + e];

  const uint4* p = (const uint4*)(Dmat + ((size_t)cloud << 20));
  unsigned long long* bestc = best + cloud * NPTS;
  const unsigned jb0 = (unsigned)(lane << 3), jb1 = 512u + jb0;

  const int row0 = blockIdx.x * 128 + wid * 32;
  for (int rr = 0; rr < 32; ++rr) {
    int row = row0 + rr;
    unsigned ci = (unsigned)comp16[row];
    uint4 ra = p[row * 128 + lane];
    uint4 rb = p[row * 128 + 64 + lane];
    unsigned key = 0xFFFFFFFFu;
    #define ENT(word, cl, ch, jb) { \
      unsigned klo = ((word) << 16) | (jb); \
      unsigned khi = ((word) & 0xFFFF0000u) | ((jb) + 1); \
      key = umin32(key, (cl) == ci ? 0xFFFFFFFFu : klo); \
      key = umin32(key, (ch) == ci ? 0xFFFFFFFFu : khi); }
    ENT(ra.x, cj[0],  cj[1],  jb0 + 0) ENT(ra.y, cj[2],  cj[3],  jb0 + 2)
    ENT(ra.z, cj[4],  cj[5],  jb0 + 4) ENT(ra.w, cj[6],  cj[7],  jb0 + 6)
    ENT(rb.x, cj[8],  cj[9],  jb1 + 0) ENT(rb.y, cj[10], cj[11], jb1 + 2)
    ENT(rb.z, cj[12], cj[13], jb1 + 4) ENT(rb.w, cj[14], cj[15], jb1 + 6)
    #undef ENT

    #define DPPMIN(ctrl) { \
      unsigned tv = (unsigned)__builtin_amdgcn_update_dpp((int)key, (int)key, (ctrl), 0xF, 0xF, false); \
      key = umin32(key, tv); }
    DPPMIN(0x111) DPPMIN(0x112) DPPMIN(0x114) DPPMIN(0x118)
    DPPMIN(0x142) DPPMIN(0x143)
    #undef DPPMIN

    if (lane == 63 && key != 0xFFFFFFFFu) {
      unsigned wv = key >> 16, v = key & 0xFFFFu;
      unsigned cmin = umin32((unsigned)row, v);
      unsigned cmax = (unsigned)row + v - cmin;
      unsigned long long k64 =
          ((unsigned long long)wv << 20) | (unsigned long long)((cmin << 10) | cmax);
      atomicMin(&bestc[ci], k64);
    }
  }

  // ---- ticket: last block of this cloud merges ----
  __threadfence();
  __syncthreads();
  __shared__ unsigned lastFlag;
  if (tid == 0) lastFlag = (atomicAdd(&ticket[cloud], 1u) == 7u) ? 1u : 0u;
  __syncthreads();
  if (!lastFlag) return;

  // ---- merge phase (256 thr x 4 nodes) ----
  __shared__ unsigned short par[NPTS];
  __shared__ unsigned cnt_sh;
  unsigned long long bk[4];
  unsigned pa[4], wb[4];
  bool app[4];
  #pragma unroll
  for (int q = 0; q < 4; ++q) {
    int i = tid + q * 256;
    bk[q] = atomicMin(&bestc[i], BMAX);  // coherent read, value unchanged
    par[i] = (unsigned short)i;
  }
  __syncthreads();
  #pragma unroll
  for (int q = 0; q < 4; ++q) {
    int i = tid + q * 256;
    unsigned cold = comp16[i];
    pa[q] = (unsigned)i; wb[q] = 0;
    if (cold == (unsigned)i && bk[q] != BMAX) {
      wb[q] = (unsigned)(bk[q] >> 20) & 0xFFFFu;
      unsigned cmin = (unsigned)(bk[q] >> 10) & 1023u;
      unsigned cmax = (unsigned)bk[q] & 1023u;
      unsigned ca = comp16[cmin], cb = comp16[cmax];
      pa[q] = (ca == (unsigned)i) ? cb : ca;
      par[i] = (unsigned short)pa[q];
    }
  }
  __syncthreads();
  #pragma unroll
  for (int q = 0; q < 4; ++q) {
    int i = tid + q * 256;
    unsigned partner = pa[q];
    unsigned pp = par[partner];
    bool twoc = (partner != (unsigned)i) && (pp == (unsigned)i);
    bool winner = twoc && ((unsigned)i < partner);
    app[q] = (partner != (unsigned)i) && !winner;
    pa[q] = winner ? 1u : 0u;
  }
  __syncthreads();
  #pragma unroll
  for (int q = 0; q < 4; ++q) {
    int i = tid + q * 256;
    if (pa[q]) par[i] = (unsigned short)i;
    if (app[q]) {
      unsigned slot = atomicAdd(&dcnt[cloud], 1u);
      deaths[(size_t)cloud * NPTS + slot] = __half2float(__ushort_as_half((unsigned short)wb[q]));
    }
  }
  __syncthreads();
  for (int it = 0; it < 10; ++it) {
    unsigned np[4];
    #pragma unroll
    for (int q = 0; q < 4; ++q) { int i = tid + q * 256; np[q] = par[par[i]]; }
    __syncthreads();
    #pragma unroll
    for (int q = 0; q < 4; ++q) { int i = tid + q * 256; par[i] = (unsigned short)np[q]; }
    __syncthreads();
  }
  if (tid == 0) cnt_sh = 0;
  __syncthreads();
  #pragma unroll
  for (int q = 0; q < 4; ++q) {
    int i = tid + q * 256;
    unsigned newc = par[comp16[i]];
    compc[i] = newc;
    bestc[i] = BMAX;
    unsigned long long bl = __ballot(newc == (unsigned)i);
    if (lane == 0) atomicAdd(&cnt_sh, (unsigned)__popcll(bl));
  }
  __syncthreads();
  if (tid == 0) ncomp[cloud] = cnt_sh;
}

// ---------------- bitonic sort kernel ----------------
__global__ __launch_bounds__(1024) void sort_kernel(float* __restrict__ buf) {
  __shared__ float s[NPTS];
  int tid = threadIdx.x;
  float* base = buf + (size_t)blockIdx.x * NPTS;
  s[tid] = base[tid];
  __syncthreads();
  for (int k = 2; k <= NPTS; k <<= 1) {
    for (int jj = k >> 1; jj > 0; jj >>= 1) {
      int i = tid;
      int l = i ^ jj;
      if (l > i) {
        float va = s[i], vb = s[l];
        bool up = ((i & k) == 0);
        if ((va > vb) == up) { s[i] = vb; s[l] = va; }
      }
      __syncthreads();
    }
  }
  base[tid] = s[tid];
}

// ---------------- fallback MSE kernel (small ws path) ----------------
__global__ __launch_bounds__(256) void mse_kernel(const float* __restrict__ a,
                                                  const float* __restrict__ b,
                                                  double* __restrict__ acc, int n4) {
  int i = blockIdx.x * blockDim.x + threadIdx.x;
  int stride = gridDim.x * blockDim.x;
  const float4* a4 = (const float4*)a;
  const float4* b4 = (const float4*)b;
  float s = 0.f;
  for (int k = i; k < n4; k += stride) {
    float4 va = a4[k], vb = b4[k];
    float dx = va.x - vb.x, dy = va.y - vb.y, dz = va.z - vb.z, dw = va.w - vb.w;
    s += dx * dx + dy * dy + dz * dz + dw * dw;
  }
  #pragma unroll
  for (int off = 32; off; off >>= 1) s += __shfl_xor(s, off);
  __shared__ float wsum[4];
  int lane = threadIdx.x & 63, wid = threadIdx.x >> 6;
  if (lane == 0) wsum[wid] = s;
  __syncthreads();
  if (threadIdx.x == 0)
    atomicAdd(acc, (double)(wsum[0] + wsum[1] + wsum[2] + wsum[3]));
}

// ---------------- fallback: fused Prim+sort from x (small ws) ----------------
__global__ __launch_bounds__(1024) void prim_kernel(const float* __restrict__ x1,
                                                    const float* __restrict__ x2,
                                                    float* __restrict__ sorted_out) {
  const int cloud = blockIdx.x;
  const int b = cloud & (BATCH - 1);
  const int src = cloud >> 4;
  const float* xbase = (src ? x2 : x1) + (size_t)b * NPTS * DIM;
  const int j = threadIdx.x;

  __shared__ float xi_sh[DIM];
  __shared__ float sq_sh[NPTS];
  __shared__ float redw[16];
  __shared__ int   redi[16];
  __shared__ float deaths[NPTS];

  const float4* xr = (const float4*)(xbase + (size_t)j * DIM);
  {
    float ax = 0.f, ay = 0.f, az = 0.f, aw = 0.f;
    #pragma unroll 8
    for (int m = 0; m < DIM / 4; ++m) {
      float4 v = xr[m];
      ax = fmaf(v.x, v.x, ax); ay = fmaf(v.y, v.y, ay);
      az = fmaf(v.z, v.z, az); aw = fmaf(v.w, v.w, aw);
    }
    sq_sh[j] = (ax + ay) + (az + aw);
  }
  const float sqj = sq_sh[j];

  float mind = BIGF;
  bool in_tree = (j == 0);
  int  cur = 0;

  for (int t = 0; t < NPTS - 1; ++t) {
    if (threadIdx.x < DIM / 4)
      ((float4*)xi_sh)[threadIdx.x] = ((const float4*)(xbase + (size_t)cur * DIM))[threadIdx.x];
    __syncthreads();

    const float4* xi4 = (const float4*)xi_sh;
    float ax = 0.f, ay = 0.f, az = 0.f, aw = 0.f;
    #pragma unroll 8
    for (int m = 0; m < DIM / 4; ++m) {
      float4 v = xr[m];
      float4 u = xi4[m];
      ax = fmaf(v.x, u.x, ax); ay = fmaf(v.y, u.y, ay);
      az = fmaf(v.z, u.z, az); aw = fmaf(v.w, u.w, aw);
    }
    float dot = (ax + ay) + (az + aw);
    float d2 = sq_sh[cur] + sqj - 2.f * dot;
    float d = sqrtf(fmaxf(d2, 0.f) + 1e-12f);
    mind = in_tree ? BIGF : fminf(mind, d);

    float w = mind;
    int idx = j;
    #pragma unroll
    for (int off = 32; off; off >>= 1) {
      float w2 = __shfl_xor(w, off);
      int i2 = __shfl_xor(idx, off);
      if (w2 < w || (w2 == w && i2 < idx)) { w = w2; idx = i2; }
    }
    int lane = j & 63, wid = j >> 6;
    if (lane == 0) { redw[wid] = w; redi[wid] = idx; }
    __syncthreads();

    float cw = redw[0];
    int ci = redi[0];
    #pragma unroll
    for (int q = 1; q < 16; ++q) {
      float w2 = redw[q]; int i2 = redi[q];
      if (w2 < cw || (w2 == cw && i2 < ci)) { cw = w2; ci = i2; }
    }
    if (j == ci) in_tree = true;
    if (j == 0)  deaths[t] = cw;
    cur = ci;
  }

  if (threadIdx.x == 0) deaths[NPTS - 1] = BIGF;
  __syncthreads();

  for (int k = 2; k <= NPTS; k <<= 1) {
    for (int jj = k >> 1; jj > 0; jj >>= 1) {
      int i = threadIdx.x;
      int l = i ^ jj;
      if (l > i) {
        float va = deaths[i], vb = deaths[l];
        bool up = ((i & k) == 0);
        if ((va > vb) == up) { deaths[i] = vb; deaths[l] = va; }
      }
      __syncthreads();
    }
  }
  sorted_out[(size_t)cloud * NPTS + threadIdx.x] = deaths[threadIdx.x];
}

// ---------------- final combine ----------------
__global__ __launch_bounds__(1024) void final_kernel(const double* __restrict__ mse_acc,
                                                     const float* __restrict__ sorted,
                                                     float* __restrict__ out) {
  int wid = threadIdx.x >> 6;
  int lane = threadIdx.x & 63;
  const float* s1 = sorted + (size_t)wid * NPTS;
  const float* s2 = sorted + (size_t)(BATCH + wid) * NPTS;
  float s = 0.f;
  for (int k = lane; k < NPTS; k += 64) {
    float dlt = s1[k] - s2[k];
    s += dlt * dlt;
  }
  #pragma unroll
  for (int off = 32; off; off >>= 1) s += __shfl_xor(s, off);
  __shared__ float part[16];
  if (lane == 0) part[wid] = sqrtf(s);
  __syncthreads();
  if (threadIdx.x == 0) {
    float topo = 0.f;
    #pragma unroll
    for (int q = 0; q < 16; ++q) topo += part[q];
    float mse = (float)(mse_acc[0] / (double)((size_t)BATCH * NPTS * DIM));
    out[0] = 1.0f * mse + 0.1f * topo;
  }
}

extern "C" void kernel_launch(void* const* d_in, const int* in_sizes, int n_in,
                              void* d_out, int out_size, void* d_ws, size_t ws_size,
                              hipStream_t stream) {
  const float* x1 = (const float*)d_in[0];
  const float* x2 = (const float*)d_in[1];
  double* mse_acc = (double*)d_ws;
  float* deaths   = (float*)((char*)d_ws + DEATHS_OFF);
  float* out      = (float*)d_out;

  hipMemsetAsync(d_ws, 0, 64, stream);

  if (ws_size >= WS_NEED) {
    unsigned short* Dmat = (unsigned short*)((char*)d_ws + D_OFF);
    unsigned short* xbf  = (unsigned short*)((char*)d_ws + XBF_OFF);
    float* sqg           = (float*)((char*)d_ws + SQ_OFF);
    unsigned* comp       = (unsigned*)((char*)d_ws + COMP_OFF);
    unsigned long long* best = (unsigned long long*)((char*)d_ws + BEST_OFF);
    unsigned* ncomp      = (unsigned*)((char*)d_ws + CNT_OFF);
    unsigned* dcnt       = ncomp + NCLOUD;
    unsigned* tickets    = (unsigned*)((char*)d_ws + TICK_OFF);

    prep_mse<<<dim3(BATCH, 8), 256, 0, stream>>>(x1, x2, xbf, sqg, comp, best,
                                                 ncomp, dcnt, deaths, tickets, mse_acc);
    distmat_mfma<<<dim3(8, 8, NCLOUD), 256, 0, stream>>>(xbf, sqg, Dmat, best);
    boruvka_merge<<<NCLOUD, 1024, 0, stream>>>(comp, best, ncomp, dcnt, deaths);
    for (int rnd = 0; rnd < NROUNDS; ++rnd)
      boruvka_round<<<dim3(8, NCLOUD), 256, 0, stream>>>(Dmat, comp, best, ncomp,
                                                         dcnt, deaths, tickets + rnd * NCLOUD);
    sort_kernel<<<NCLOUD, 1024, 0, stream>>>(deaths);
  } else {
    int n4 = (BATCH * NPTS * DIM) / 4;
    mse_kernel<<<1024, 256, 0, stream>>>(x1, x2, mse_acc, n4);
    prim_kernel<<<NCLOUD, 1024, 0, stream>>>(x1, x2, deaths);
  }

  final_kernel<<<1, 1024, 0, stream>>>(mse_acc, deaths, out);
}